// Round 9
// baseline (361.445 us; speedup 1.0000x reference)
//
#include <hip/hip_runtime.h>

#define N_NODES 327680
#define N_EDGES 2621440
#define NGRAPH  8192
#define NB      640          // dst buckets (512 nodes each)
#define BCAPE   4608         // fixed per-bucket capacity (mean 4096, +8 sigma)

typedef unsigned int uint;
typedef unsigned short u16;
typedef __attribute__((ext_vector_type(8))) short s16x8;
typedef __attribute__((ext_vector_type(4))) float f32x4;

__device__ __forceinline__ float bl(uint u){ return __uint_as_float(u << 16); }
__device__ __forceinline__ float bh(uint u){ return __uint_as_float(u & 0xffff0000u); }
__device__ __forceinline__ u16 f2b(float f){
    uint u = __float_as_uint(f);
    u += 0x7fffu + ((u>>16)&1u);          // round-to-nearest-even
    return (u16)(u>>16);
}
__device__ __forceinline__ uint pk(float a, float b){
    return (uint)f2b(a) | ((uint)f2b(b) << 16);
}

// ---------------- prep: weight transposes (bf16) + gcur zero, one launch ----------------

__device__ void tr_tile(const float* __restrict__ in, u16* __restrict__ out,
                        int K, int N, int Kpad, int kb, int nb){
    __shared__ u16 t[64][72];
    for (int i = threadIdx.x; i < 4096; i += 256){
        int k = i >> 6, n = i & 63;
        int gk = kb + k, gn = nb + n;
        float v = (gk < K && gn < N) ? in[(size_t)gk*N + gn] : 0.f;
        t[n][k] = f2b(v);
    }
    __syncthreads();
    for (int i = threadIdx.x; i < 4096; i += 256){
        int n = i >> 6, k = i & 63;
        int gk = kb + k, gn = nb + n;
        if (gn < N && gk < Kpad) out[(size_t)gn*Kpad + gk] = t[n][k];
    }
}

__global__ __launch_bounds__(256) void k_prep(
    const float* __restrict__ W1, const float* __restrict__ W2,
    const float* __restrict__ l1w, const float* __restrict__ l2w,
    u16* __restrict__ w1t, u16* __restrict__ w2t,
    u16* __restrict__ l1wt, u16* __restrict__ l2wt, int* __restrict__ gcur)
{
    int b = blockIdx.x;
    if (b < 120)      tr_tile(l1w, l1wt, 1920, 256, 1920, (b%30)*64, (b/30)*64);
    else if (b < 124) tr_tile(l2w, l2wt, 256,  64,  256,  (b-120)*64, 0);
    else if (b < 126) tr_tile(W1,  w1t,  58,   96,  64,   0, (b-124)*64);
    else if (b < 128) tr_tile(W2,  w2t,  96,   48,  96,   (b-126)*64, 0);
    else {
        for (int i = threadIdx.x; i < NB; i += 256) gcur[i] = 0;
    }
}

// ---------------- partition edges into fixed-cap dst-buckets (packed uint) ----------------

__global__ __launch_bounds__(256) void k_partition(
    const int* __restrict__ src, const int* __restrict__ dst,
    int* __restrict__ gcur, uint* __restrict__ staging)
{
    __shared__ int cnt[NB], base_[NB];
    int tid = threadIdx.x;
    for (int i = tid; i < NB; i += 256) cnt[i] = 0;
    __syncthreads();
    int e0 = blockIdx.x*4096;
    int d[16];
    #pragma unroll
    for (int j = 0; j < 16; ++j){
        d[j] = dst[e0 + j*256 + tid];
        atomicAdd(&cnt[d[j] >> 9], 1);
    }
    __syncthreads();
    for (int i = tid; i < NB; i += 256)
        base_[i] = atomicAdd(&gcur[i], cnt[i]);
    __syncthreads();
    for (int i = tid; i < NB; i += 256) cnt[i] = 0;
    __syncthreads();
    #pragma unroll
    for (int j = 0; j < 16; ++j){
        int e = e0 + j*256 + tid;
        int b = d[j] >> 9;
        int r = atomicAdd(&cnt[b], 1);
        staging[(uint)b*BCAPE + base_[b] + r] = (uint)src[e] | ((uint)(d[j] & 511) << 19);
    }
}

// ---- per-bucket: degree, dinv, row starts, csr place, degree-sorted perm, x prescale ----

__global__ __launch_bounds__(512) void k_bucket(
    const uint* __restrict__ staging, const int* __restrict__ gcur,
    const float* __restrict__ x,
    int* __restrict__ rowst, int* __restrict__ rendg, float* __restrict__ dinvg,
    int* __restrict__ csr, int* __restrict__ perm, uint* __restrict__ xs32)
{
    __shared__ uint sedge[BCAPE];
    __shared__ int deg[512];
    __shared__ int sc[512];
    __shared__ int cur[512];
    __shared__ int dh[64], dbase[64];
    __shared__ float sdinv[512];
    const int b = blockIdx.x;
    const int tid = threadIdx.x;
    const int lo = b*BCAPE;
    int cnt = gcur[b];
    if (cnt > BCAPE) cnt = BCAPE;   // safety (8-sigma margin, never expected)
    deg[tid] = 0;
    if (tid < 64) dh[tid] = 0;
    __syncthreads();
    for (int t = tid; t < cnt; t += 512){
        uint ed = staging[lo + t];
        sedge[t] = ed;
        atomicAdd(&deg[ed >> 19], 1);
    }
    __syncthreads();
    int d = deg[tid];
    sc[tid] = d;
    __syncthreads();
    for (int o = 1; o < 512; o <<= 1){
        int v = (tid >= o) ? sc[tid-o] : 0;
        __syncthreads();
        sc[tid] += v;
        __syncthreads();
    }
    int incl = sc[tid];
    int excl = incl - d;
    int gnode = b*512 + tid;
    float dv = 1.0f / sqrtf((float)(d + 1));
    rowst[gnode] = lo + excl;
    rendg[gnode] = lo + incl;
    dinvg[gnode] = dv;
    sdinv[tid] = dv;
    cur[tid] = lo + excl;
    int bin = min(d, 63);
    atomicAdd(&dh[bin], 1);
    __syncthreads();
    if (tid == 0){
        int a = 0;
        #pragma unroll
        for (int i = 0; i < 64; ++i){ dbase[i] = a; a += dh[i]; dh[i] = 0; }
    }
    __syncthreads();
    int pos = dbase[bin] + atomicAdd(&dh[bin], 1);
    perm[b*512 + pos] = gnode;
    for (int t = tid; t < cnt; t += 512){
        uint ed = sedge[t];
        int p = atomicAdd(&cur[ed >> 19], 1);
        csr[p] = (int)(ed & 0x7FFFFu);
    }
    // prescale this bucket's 512 nodes: xs[node][32] = pk(x*dinv), pad cols>=58
    const size_t n0 = (size_t)b*512;
    for (int i = tid; i < 512*32; i += 512){
        int n = i >> 5, c = i & 31;
        float dvn = sdinv[n];
        float a = 0.f, bb = 0.f;
        if (c < 29){
            float2 v = *(const float2*)&x[(n0 + n)*58 + 2*c];
            a = v.x * dvn; bb = v.y * dvn;
        }
        xs32[(n0 + n)*32 + c] = pk(a, bb);
    }
}

// ---- conv1 gather: 8 lanes/node x uint4 (16B), 8 edges batched, degree-sorted perm ----

__global__ __launch_bounds__(256) void k_gather1(
    const int* __restrict__ rs, const int* __restrict__ re,
    const int* __restrict__ csr, const float* __restrict__ dinv,
    const int* __restrict__ perm,
    const uint4* __restrict__ feat4,   // xs [N] rows of 128B packed bf16
    u16* __restrict__ out)             // agg1 [N][64]
{
    int slot = (blockIdx.x*256 + threadIdx.x) >> 3;
    int c4 = threadIdx.x & 7;
    int node = perm[slot];
    uint4 u = feat4[((uint)node << 3) + c4];
    float a0 = bl(u.x), a1 = bh(u.x), a2 = bl(u.y), a3 = bh(u.y);
    float a4 = bl(u.z), a5 = bh(u.z), a6 = bl(u.w), a7 = bh(u.w);
    int e = rs[node];
    const int e1 = re[node];
    while (e < e1){
        const int last = e1 - 1;
        int idx[8];
        #pragma unroll
        for (int k = 0; k < 8; ++k) idx[k] = csr[min(e + k, last)];
        uint4 uu[8];
        #pragma unroll
        for (int k = 0; k < 8; ++k) uu[k] = feat4[((uint)idx[k] << 3) + c4];
        #pragma unroll
        for (int k = 0; k < 8; ++k){
            if (e + k < e1){
                a0 += bl(uu[k].x); a1 += bh(uu[k].x);
                a2 += bl(uu[k].y); a3 += bh(uu[k].y);
                a4 += bl(uu[k].z); a5 += bh(uu[k].z);
                a6 += bl(uu[k].w); a7 += bh(uu[k].w);
            }
        }
        e += 8;
    }
    float di = dinv[node];
    a0 *= di; a1 *= di; a2 *= di; a3 *= di;
    a4 *= di; a5 *= di; a6 *= di; a7 *= di;
    uint4 w;
    w.x = pk(a0,a1); w.y = pk(a2,a3); w.z = pk(a4,a5); w.w = pk(a6,a7);
    *(uint4*)&out[(size_t)node*64 + c4*8] = w;
}

// ---------------- conv MLP: ts = (relu(agg1 @ W1 + b1) @ W2) * dinv  (MFMA) ----------------

__global__ __launch_bounds__(256) void k_conv_mlp(
    const u16* __restrict__ A,      // agg1 [N][64] (58 real cols, rest 0)
    const u16* __restrict__ w1t,    // [96][64] bf16 (transposed, k-padded)
    const float* __restrict__ b1,   // [96]
    const u16* __restrict__ w2t,    // [48][96] bf16 (transposed)
    const float* __restrict__ dinv,
    u16* __restrict__ ts)           // dense [N][48], prescaled by dinv
{
    __shared__ __align__(16) u16 As[64][72];
    __shared__ __align__(16) u16 Bt1[96][72];
    __shared__ __align__(16) u16 Bt2[48][104];
    __shared__ __align__(16) u16 sh1[64][104];
    __shared__ float sb1[96];
    const int tid = threadIdx.x;
    {
        const u16* Ab = A + (size_t)blockIdx.x*64*64;
        for (int i = tid; i < 512; i += 256){
            int r = i >> 3, s = i & 7;
            *(uint4*)&As[r][s*8] = *(const uint4*)&Ab[r*64 + s*8];
        }
    }
    for (int i = tid; i < 768; i += 256){
        int n = i >> 3, s = i & 7;
        *(uint4*)&Bt1[n][s*8] = *(const uint4*)&w1t[n*64 + s*8];
    }
    for (int i = tid; i < 576; i += 256){
        int n = i / 12, s = i % 12;
        *(uint4*)&Bt2[n][s*8] = *(const uint4*)&w2t[n*96 + s*8];
    }
    if (tid < 96) sb1[tid] = b1[tid];
    __syncthreads();

    const int wv = tid >> 6, l = tid & 63;
    const int lr = l & 15, lg = l >> 4;
    const int r0 = wv*16;

    f32x4 acc1[6] = {};
    #pragma unroll
    for (int s = 0; s < 2; ++s){
        s16x8 af = *(const s16x8*)&As[r0+lr][s*32 + lg*8];
        #pragma unroll
        for (int t = 0; t < 6; ++t){
            s16x8 bf = *(const s16x8*)&Bt1[t*16+lr][s*32 + lg*8];
            acc1[t] = __builtin_amdgcn_mfma_f32_16x16x32_bf16(af, bf, acc1[t], 0, 0, 0);
        }
    }
    #pragma unroll
    for (int t = 0; t < 6; ++t){
        int col = t*16 + lr;
        float bias = sb1[col];
        #pragma unroll
        for (int r = 0; r < 4; ++r)
            sh1[r0 + lg*4 + r][col] = f2b(fmaxf(acc1[t][r] + bias, 0.f));
    }
    __syncthreads();

    f32x4 acc2[3] = {};
    #pragma unroll
    for (int s = 0; s < 3; ++s){
        s16x8 af = *(const s16x8*)&sh1[r0+lr][s*32 + lg*8];
        #pragma unroll
        for (int t = 0; t < 3; ++t){
            s16x8 bf = *(const s16x8*)&Bt2[t*16+lr][s*32 + lg*8];
            acc2[t] = __builtin_amdgcn_mfma_f32_16x16x32_bf16(af, bf, acc2[t], 0, 0, 0);
        }
    }
    size_t gbase = (size_t)blockIdx.x*64;
    #pragma unroll
    for (int r = 0; r < 4; ++r){
        size_t row = gbase + r0 + lg*4 + r;
        float dv = dinv[row];
        #pragma unroll
        for (int t = 0; t < 3; ++t)
            ts[row*48 + t*16 + lr] = f2b(acc2[t][r] * dv);
    }
}

// ---- conv2 gather: 8 lanes/node x uint3 (12B, dense 48), 8 edges batched ----

__global__ __launch_bounds__(256) void k_gather2(
    const int* __restrict__ rs, const int* __restrict__ re,
    const int* __restrict__ csr, const float* __restrict__ dinv,
    const int* __restrict__ perm,
    const uint* __restrict__ feat,     // ts as uint[N][24] (dense 48 bf16)
    const float* __restrict__ bias,
    uint* __restrict__ out)            // agg2 as uint[N][24]
{
    int slot = (blockIdx.x*256 + threadIdx.x) >> 3;
    int c4 = threadIdx.x & 7;
    int node = perm[slot];
    uint3 u = *(const uint3*)&feat[(size_t)node*24 + c4*3];
    float a0 = bl(u.x), a1 = bh(u.x), a2 = bl(u.y), a3 = bh(u.y);
    float a4 = bl(u.z), a5 = bh(u.z);
    int e = rs[node];
    const int e1 = re[node];
    while (e < e1){
        const int last = e1 - 1;
        int idx[8];
        #pragma unroll
        for (int k = 0; k < 8; ++k) idx[k] = csr[min(e + k, last)];
        uint3 uu[8];
        #pragma unroll
        for (int k = 0; k < 8; ++k) uu[k] = *(const uint3*)&feat[(size_t)idx[k]*24 + c4*3];
        #pragma unroll
        for (int k = 0; k < 8; ++k){
            if (e + k < e1){
                a0 += bl(uu[k].x); a1 += bh(uu[k].x);
                a2 += bl(uu[k].y); a3 += bh(uu[k].y);
                a4 += bl(uu[k].z); a5 += bh(uu[k].z);
            }
        }
        e += 8;
    }
    float di = dinv[node];
    a0 = fmaxf(a0*di + bias[6*c4+0], 0.f);
    a1 = fmaxf(a1*di + bias[6*c4+1], 0.f);
    a2 = fmaxf(a2*di + bias[6*c4+2], 0.f);
    a3 = fmaxf(a3*di + bias[6*c4+3], 0.f);
    a4 = fmaxf(a4*di + bias[6*c4+4], 0.f);
    a5 = fmaxf(a5*di + bias[6*c4+5], 0.f);
    uint3 w;
    w.x = pk(a0,a1); w.y = pk(a2,a3); w.z = pk(a4,a5);
    *(uint3*)&out[(size_t)node*24 + c4*3] = w;
}

// ---------------- fused MLP head: 32 graphs/block, g1 in LDS, l2/l3 fused ----------------

__global__ __launch_bounds__(256) void k_head(
    const u16* __restrict__ A,      // agg2, graph rows [8192][1920] bf16
    const u16* __restrict__ l1wt,   // [256][1920]
    const float* __restrict__ l1b,
    const u16* __restrict__ l2wt,   // [64][256]
    const float* __restrict__ l2b,
    const float* __restrict__ l3w, const float* __restrict__ l3b,
    float* __restrict__ out)
{
    __shared__ __align__(16) u16 As[32][72];
    __shared__ __align__(16) u16 Bt[256][72];
    __shared__ float part[32][2];
    u16 (*sh1)[264] = (u16(*)[264])&Bt[0][0];
    const int tid = threadIdx.x;
    const int g0 = blockIdx.x*32;
    const int w = tid >> 6, l = tid & 63;
    const int lr = l & 15, lg = l >> 4;
    const int r0 = (w & 1)*16;
    const int c0 = (w >> 1)*128;
    f32x4 acc[8] = {};
    for (int k0 = 0; k0 < 1920; k0 += 64){
        __syncthreads();
        {
            int r = tid >> 3, s = tid & 7;
            *(uint4*)&As[r][s*8] = *(const uint4*)&A[(size_t)(g0+r)*1920 + k0 + s*8];
        }
        for (int i = tid; i < 2048; i += 256){
            int n = i >> 3, s = i & 7;
            *(uint4*)&Bt[n][s*8] = *(const uint4*)&l1wt[(size_t)n*1920 + k0 + s*8];
        }
        __syncthreads();
        #pragma unroll
        for (int s = 0; s < 2; ++s){
            s16x8 af = *(const s16x8*)&As[r0+lr][s*32 + lg*8];
            #pragma unroll
            for (int t = 0; t < 8; ++t){
                s16x8 bf = *(const s16x8*)&Bt[c0 + t*16 + lr][s*32 + lg*8];
                acc[t] = __builtin_amdgcn_mfma_f32_16x16x32_bf16(af, bf, acc[t], 0, 0, 0);
            }
        }
    }
    __syncthreads();   // everyone done reading Bt before overlay write
    #pragma unroll
    for (int t = 0; t < 8; ++t){
        int col = c0 + t*16 + lr;
        float bs = l1b[col];
        #pragma unroll
        for (int r = 0; r < 4; ++r)
            sh1[r0 + lg*4 + r][col] = f2b(fmaxf(acc[t][r] + bs, 0.f));
    }
    __syncthreads();
    f32x4 acc2[2] = {};
    #pragma unroll
    for (int s = 0; s < 8; ++s){
        s16x8 af = *(const s16x8*)&sh1[r0+lr][s*32 + lg*8];
        #pragma unroll
        for (int t = 0; t < 2; ++t){
            int col = (w>>1)*32 + t*16 + lr;
            s16x8 bf = *(const s16x8*)&l2wt[(size_t)col*256 + s*32 + lg*8];
            acc2[t] = __builtin_amdgcn_mfma_f32_16x16x32_bf16(af, bf, acc2[t], 0, 0, 0);
        }
    }
    float p[4];
    #pragma unroll
    for (int r = 0; r < 4; ++r){
        p[r] = 0.f;
        #pragma unroll
        for (int t = 0; t < 2; ++t){
            int col = (w>>1)*32 + t*16 + lr;
            p[r] += fmaxf(acc2[t][r] + l2b[col], 0.f) * l3w[col];
        }
    }
    #pragma unroll
    for (int o = 1; o < 16; o <<= 1){
        #pragma unroll
        for (int r = 0; r < 4; ++r) p[r] += __shfl_xor(p[r], o);
    }
    if (lr == 0){
        #pragma unroll
        for (int r = 0; r < 4; ++r)
            part[r0 + lg*4 + r][w>>1] = p[r];
    }
    __syncthreads();
    if (tid < 32)
        out[g0 + tid] = 1.0f / (1.0f + expf(-(part[tid][0] + part[tid][1] + l3b[0])));
}

extern "C" void kernel_launch(void* const* d_in, const int* in_sizes, int n_in,
                              void* d_out, int out_size, void* d_ws, size_t ws_size,
                              hipStream_t stream){
    const float* x   = (const float*)d_in[0];
    const int*   ei  = (const int*)  d_in[1];
    const int*   src = ei;
    const int*   dst = ei + N_EDGES;
    const float* W1  = (const float*)d_in[2];
    const float* b1  = (const float*)d_in[3];
    const float* W2  = (const float*)d_in[4];
    const float* b2  = (const float*)d_in[5];
    const float* l1w = (const float*)d_in[6];
    const float* l1b = (const float*)d_in[7];
    const float* l2w = (const float*)d_in[8];
    const float* l2b = (const float*)d_in[9];
    const float* l3w = (const float*)d_in[10];
    const float* l3b = (const float*)d_in[11];
    float* out = (float*)d_out;

    char* w = (char*)d_ws;
    auto alloc = [&](size_t bytes){ void* p = (void*)w; w += (bytes + 255) & ~(size_t)255; return p; };
    float* dinv    = (float*)alloc((size_t)N_NODES*4);
    int*   rowst   = (int*)  alloc((size_t)N_NODES*4);
    int*   rend    = (int*)  alloc((size_t)N_NODES*4);
    int*   perm    = (int*)  alloc((size_t)N_NODES*4);
    int*   gcur    = (int*)  alloc(NB*4);
    u16*   w1t     = (u16*)  alloc(96*64*2);
    u16*   w2t     = (u16*)  alloc(48*96*2);
    u16*   l1wt    = (u16*)  alloc((size_t)256*1920*2);
    u16*   l2wt    = (u16*)  alloc((size_t)64*256*2);
    int*   csr     = (int*)  alloc((size_t)NB*BCAPE*4);
    uint*  staging = (uint*) alloc((size_t)NB*BCAPE*4);
    char*  BUF_P   = (char*) alloc((size_t)N_NODES*32*4);   // xs32 -> ts
    char*  BUF_Q   = (char*) alloc((size_t)N_NODES*64*2);   // agg1 -> agg2

    uint* xs32 = (uint*)BUF_P;          // [bucket .. gather1]
    u16*  ts   = (u16*) BUF_P;          // [conv_mlp .. gather2]  (30MB of 42MB)
    u16*  agg1 = (u16*) BUF_Q;          // [gather1 .. conv_mlp]
    u16*  agg2 = (u16*) BUF_Q;          // [gather2 .. head]      (30MB of 42MB)

    // prep: weight transposes + gcur zero (one launch)
    k_prep     <<<129, 256, 0, stream>>>(W1, W2, l1w, l2w, w1t, w2t, l1wt, l2wt, gcur);

    // bucketed CSR build (fixed-cap buckets) + fused x prescale
    k_partition<<<640, 256, 0, stream>>>(src, dst, gcur, staging);
    k_bucket   <<<640, 512, 0, stream>>>(staging, gcur, x, rowst, rend, dinv, csr, perm, xs32);

    // conv1: gather -> MFMA conv (dense-48 prescaled output)
    k_gather1  <<<10240, 256, 0, stream>>>(rowst, rend, csr, dinv, perm,
                                           (const uint4*)xs32, agg1);
    k_conv_mlp <<<5120,  256, 0, stream>>>(agg1, w1t, b1, w2t, dinv, ts);

    // conv2: gather (dense 48) + bias + relu -> agg2
    k_gather2  <<<10240, 256, 0, stream>>>(rowst, rend, csr, dinv, perm,
                                           (const uint*)ts, b2, (uint*)agg2);

    // fused MLP head
    k_head     <<<256, 256, 0, stream>>>(agg2, l1wt, l1b, l2wt, l2b, l3w, l3b, out);
}

// Round 10
// 339.399 us; speedup vs baseline: 1.0650x; 1.0650x over previous
//
#include <hip/hip_runtime.h>

#define N_NODES 327680
#define N_EDGES 2621440
#define NGRAPH  8192
#define NB      640          // dst buckets (512 nodes each)
#define BCAPE   4608         // fixed per-bucket capacity (mean 4096, +8 sigma)

typedef unsigned int uint;
typedef unsigned short u16;
typedef __attribute__((ext_vector_type(8))) short s16x8;
typedef __attribute__((ext_vector_type(4))) float f32x4;

__device__ __forceinline__ float bl(uint u){ return __uint_as_float(u << 16); }
__device__ __forceinline__ float bh(uint u){ return __uint_as_float(u & 0xffff0000u); }
__device__ __forceinline__ u16 f2b(float f){
    uint u = __float_as_uint(f);
    u += 0x7fffu + ((u>>16)&1u);          // round-to-nearest-even
    return (u16)(u>>16);
}
__device__ __forceinline__ uint pk(float a, float b){
    return (uint)f2b(a) | ((uint)f2b(b) << 16);
}

// ---------------- prep: weight transposes (bf16) + gcur zero, one launch ----------------

__device__ void tr_tile(const float* __restrict__ in, u16* __restrict__ out,
                        int K, int N, int Kpad, int kb, int nb){
    __shared__ u16 t[64][72];
    for (int i = threadIdx.x; i < 4096; i += 256){
        int k = i >> 6, n = i & 63;
        int gk = kb + k, gn = nb + n;
        float v = (gk < K && gn < N) ? in[(size_t)gk*N + gn] : 0.f;
        t[n][k] = f2b(v);
    }
    __syncthreads();
    for (int i = threadIdx.x; i < 4096; i += 256){
        int n = i >> 6, k = i & 63;
        int gk = kb + k, gn = nb + n;
        if (gn < N && gk < Kpad) out[(size_t)gn*Kpad + gk] = t[n][k];
    }
}

__global__ __launch_bounds__(256) void k_prep(
    const float* __restrict__ W1, const float* __restrict__ W2,
    const float* __restrict__ l1w, const float* __restrict__ l2w,
    u16* __restrict__ w1t, u16* __restrict__ w2t,
    u16* __restrict__ l1wt, u16* __restrict__ l2wt, int* __restrict__ gcur)
{
    int b = blockIdx.x;
    if (b < 120)      tr_tile(l1w, l1wt, 1920, 256, 1920, (b%30)*64, (b/30)*64);
    else if (b < 124) tr_tile(l2w, l2wt, 256,  64,  256,  (b-120)*64, 0);
    else if (b < 126) tr_tile(W1,  w1t,  58,   96,  64,   0, (b-124)*64);
    else if (b < 128) tr_tile(W2,  w2t,  96,   48,  96,   (b-126)*64, 0);
    else {
        for (int i = threadIdx.x; i < NB; i += 256) gcur[i] = 0;
    }
}

// ---------------- partition edges into fixed-cap dst-buckets (packed uint) ----------------

__global__ __launch_bounds__(256) void k_partition(
    const int* __restrict__ src, const int* __restrict__ dst,
    int* __restrict__ gcur, uint* __restrict__ staging)
{
    __shared__ int cnt[NB], base_[NB];
    int tid = threadIdx.x;
    for (int i = tid; i < NB; i += 256) cnt[i] = 0;
    __syncthreads();
    int e0 = blockIdx.x*4096;
    int d[16];
    #pragma unroll
    for (int j = 0; j < 16; ++j){
        d[j] = dst[e0 + j*256 + tid];
        atomicAdd(&cnt[d[j] >> 9], 1);
    }
    __syncthreads();
    for (int i = tid; i < NB; i += 256)
        base_[i] = atomicAdd(&gcur[i], cnt[i]);
    __syncthreads();
    for (int i = tid; i < NB; i += 256) cnt[i] = 0;
    __syncthreads();
    #pragma unroll
    for (int j = 0; j < 16; ++j){
        int e = e0 + j*256 + tid;
        int b = d[j] >> 9;
        int r = atomicAdd(&cnt[b], 1);
        staging[(uint)b*BCAPE + base_[b] + r] = (uint)src[e] | ((uint)(d[j] & 511) << 19);
    }
}

// ---- per-bucket: degree, dinv, row starts, csr place, degree-sorted perm, x prescale ----

__global__ __launch_bounds__(512) void k_bucket(
    const uint* __restrict__ staging, const int* __restrict__ gcur,
    const float* __restrict__ x,
    int* __restrict__ rowst, int* __restrict__ rendg, float* __restrict__ dinvg,
    int* __restrict__ csr, int* __restrict__ perm, uint* __restrict__ xs32)
{
    __shared__ uint sedge[BCAPE];
    __shared__ int deg[512];
    __shared__ int sc[512];
    __shared__ int cur[512];
    __shared__ int dh[64], dbase[64];
    __shared__ float sdinv[512];
    const int b = blockIdx.x;
    const int tid = threadIdx.x;
    const int lo = b*BCAPE;
    int cnt = gcur[b];
    if (cnt > BCAPE) cnt = BCAPE;   // safety (8-sigma margin, never expected)
    deg[tid] = 0;
    if (tid < 64) dh[tid] = 0;
    __syncthreads();
    for (int t = tid; t < cnt; t += 512){
        uint ed = staging[lo + t];
        sedge[t] = ed;
        atomicAdd(&deg[ed >> 19], 1);
    }
    __syncthreads();
    int d = deg[tid];
    sc[tid] = d;
    __syncthreads();
    for (int o = 1; o < 512; o <<= 1){
        int v = (tid >= o) ? sc[tid-o] : 0;
        __syncthreads();
        sc[tid] += v;
        __syncthreads();
    }
    int incl = sc[tid];
    int excl = incl - d;
    int gnode = b*512 + tid;
    float dv = 1.0f / sqrtf((float)(d + 1));
    rowst[gnode] = lo + excl;
    rendg[gnode] = lo + incl;
    dinvg[gnode] = dv;
    sdinv[tid] = dv;
    cur[tid] = lo + excl;
    int bin = min(d, 63);
    atomicAdd(&dh[bin], 1);
    __syncthreads();
    if (tid == 0){
        int a = 0;
        #pragma unroll
        for (int i = 0; i < 64; ++i){ dbase[i] = a; a += dh[i]; dh[i] = 0; }
    }
    __syncthreads();
    int pos = dbase[bin] + atomicAdd(&dh[bin], 1);
    perm[b*512 + pos] = gnode;
    for (int t = tid; t < cnt; t += 512){
        uint ed = sedge[t];
        int p = atomicAdd(&cur[ed >> 19], 1);
        csr[p] = (int)(ed & 0x7FFFFu);
    }
    // prescale this bucket's 512 nodes: xs[node][32] = pk(x*dinv), pad cols>=58
    const size_t n0 = (size_t)b*512;
    for (int i = tid; i < 512*32; i += 512){
        int n = i >> 5, c = i & 31;
        float dvn = sdinv[n];
        float a = 0.f, bb = 0.f;
        if (c < 29){
            float2 v = *(const float2*)&x[(n0 + n)*58 + 2*c];
            a = v.x * dvn; bb = v.y * dvn;
        }
        xs32[(n0 + n)*32 + c] = pk(a, bb);
    }
}

// ---- conv1 gather: 8 lanes/node x uint4 (16B), 8 edges batched, degree-sorted perm ----

__global__ __launch_bounds__(256) void k_gather1(
    const int* __restrict__ rs, const int* __restrict__ re,
    const int* __restrict__ csr, const float* __restrict__ dinv,
    const int* __restrict__ perm,
    const uint4* __restrict__ feat4,   // xs [N] rows of 128B packed bf16
    u16* __restrict__ out)             // agg1 [N][64]
{
    int slot = (blockIdx.x*256 + threadIdx.x) >> 3;
    int c4 = threadIdx.x & 7;
    int node = perm[slot];
    uint4 u = feat4[((uint)node << 3) + c4];
    float a0 = bl(u.x), a1 = bh(u.x), a2 = bl(u.y), a3 = bh(u.y);
    float a4 = bl(u.z), a5 = bh(u.z), a6 = bl(u.w), a7 = bh(u.w);
    int e = rs[node];
    const int e1 = re[node];
    while (e < e1){
        const int last = e1 - 1;
        int idx[8];
        #pragma unroll
        for (int k = 0; k < 8; ++k) idx[k] = csr[min(e + k, last)];
        uint4 uu[8];
        #pragma unroll
        for (int k = 0; k < 8; ++k) uu[k] = feat4[((uint)idx[k] << 3) + c4];
        #pragma unroll
        for (int k = 0; k < 8; ++k){
            if (e + k < e1){
                a0 += bl(uu[k].x); a1 += bh(uu[k].x);
                a2 += bl(uu[k].y); a3 += bh(uu[k].y);
                a4 += bl(uu[k].z); a5 += bh(uu[k].z);
                a6 += bl(uu[k].w); a7 += bh(uu[k].w);
            }
        }
        e += 8;
    }
    float di = dinv[node];
    a0 *= di; a1 *= di; a2 *= di; a3 *= di;
    a4 *= di; a5 *= di; a6 *= di; a7 *= di;
    uint4 w;
    w.x = pk(a0,a1); w.y = pk(a2,a3); w.z = pk(a4,a5); w.w = pk(a6,a7);
    *(uint4*)&out[(size_t)node*64 + c4*8] = w;
}

// ---------------- conv MLP: ts = (relu(agg1 @ W1 + b1) @ W2) * dinv  (MFMA) ----------------

__global__ __launch_bounds__(256) void k_conv_mlp(
    const u16* __restrict__ A,      // agg1 [N][64] (58 real cols, rest 0)
    const u16* __restrict__ w1t,    // [96][64] bf16 (transposed, k-padded)
    const float* __restrict__ b1,   // [96]
    const u16* __restrict__ w2t,    // [48][96] bf16 (transposed)
    const float* __restrict__ dinv,
    u16* __restrict__ ts)           // [N][64], cols>=48 zeroed (prescaled by dinv)
{
    __shared__ __align__(16) u16 As[64][72];
    __shared__ __align__(16) u16 Bt1[96][72];
    __shared__ __align__(16) u16 Bt2[48][104];
    __shared__ __align__(16) u16 sh1[64][104];
    __shared__ float sb1[96];
    const int tid = threadIdx.x;
    {
        const u16* Ab = A + (size_t)blockIdx.x*64*64;
        for (int i = tid; i < 512; i += 256){
            int r = i >> 3, s = i & 7;
            *(uint4*)&As[r][s*8] = *(const uint4*)&Ab[r*64 + s*8];
        }
    }
    for (int i = tid; i < 768; i += 256){
        int n = i >> 3, s = i & 7;
        *(uint4*)&Bt1[n][s*8] = *(const uint4*)&w1t[n*64 + s*8];
    }
    for (int i = tid; i < 576; i += 256){
        int n = i / 12, s = i % 12;
        *(uint4*)&Bt2[n][s*8] = *(const uint4*)&w2t[n*96 + s*8];
    }
    if (tid < 96) sb1[tid] = b1[tid];
    __syncthreads();

    const int wv = tid >> 6, l = tid & 63;
    const int lr = l & 15, lg = l >> 4;
    const int r0 = wv*16;

    f32x4 acc1[6] = {};
    #pragma unroll
    for (int s = 0; s < 2; ++s){
        s16x8 af = *(const s16x8*)&As[r0+lr][s*32 + lg*8];
        #pragma unroll
        for (int t = 0; t < 6; ++t){
            s16x8 bf = *(const s16x8*)&Bt1[t*16+lr][s*32 + lg*8];
            acc1[t] = __builtin_amdgcn_mfma_f32_16x16x32_bf16(af, bf, acc1[t], 0, 0, 0);
        }
    }
    #pragma unroll
    for (int t = 0; t < 6; ++t){
        int col = t*16 + lr;
        float bias = sb1[col];
        #pragma unroll
        for (int r = 0; r < 4; ++r)
            sh1[r0 + lg*4 + r][col] = f2b(fmaxf(acc1[t][r] + bias, 0.f));
    }
    __syncthreads();

    f32x4 acc2[3] = {};
    #pragma unroll
    for (int s = 0; s < 3; ++s){
        s16x8 af = *(const s16x8*)&sh1[r0+lr][s*32 + lg*8];
        #pragma unroll
        for (int t = 0; t < 3; ++t){
            s16x8 bf = *(const s16x8*)&Bt2[t*16+lr][s*32 + lg*8];
            acc2[t] = __builtin_amdgcn_mfma_f32_16x16x32_bf16(af, bf, acc2[t], 0, 0, 0);
        }
    }
    size_t gbase = (size_t)blockIdx.x*64;
    #pragma unroll
    for (int r = 0; r < 4; ++r){
        size_t row = gbase + r0 + lg*4 + r;
        float dv = dinv[row];
        #pragma unroll
        for (int t = 0; t < 3; ++t)
            ts[row*64 + t*16 + lr] = f2b(acc2[t][r] * dv);
        ts[row*64 + 48 + lr] = 0;
    }
}

// ---- conv2 gather: 8 lanes/node x uint4 from padded-64 ts, dense-48 masked write ----

__global__ __launch_bounds__(256) void k_gather2(
    const int* __restrict__ rs, const int* __restrict__ re,
    const int* __restrict__ csr, const float* __restrict__ dinv,
    const int* __restrict__ perm,
    const uint4* __restrict__ feat4,   // ts [N] rows of 128B packed bf16 (48 real)
    const float* __restrict__ bias,
    u16* __restrict__ out)             // agg2 dense [N][48]
{
    int slot = (blockIdx.x*256 + threadIdx.x) >> 3;
    int c4 = threadIdx.x & 7;
    int node = perm[slot];
    uint4 u = feat4[((uint)node << 3) + c4];
    float a0 = bl(u.x), a1 = bh(u.x), a2 = bl(u.y), a3 = bh(u.y);
    float a4 = bl(u.z), a5 = bh(u.z), a6 = bl(u.w), a7 = bh(u.w);
    int e = rs[node];
    const int e1 = re[node];
    while (e < e1){
        const int last = e1 - 1;
        int idx[8];
        #pragma unroll
        for (int k = 0; k < 8; ++k) idx[k] = csr[min(e + k, last)];
        uint4 uu[8];
        #pragma unroll
        for (int k = 0; k < 8; ++k) uu[k] = feat4[((uint)idx[k] << 3) + c4];
        #pragma unroll
        for (int k = 0; k < 8; ++k){
            if (e + k < e1){
                a0 += bl(uu[k].x); a1 += bh(uu[k].x);
                a2 += bl(uu[k].y); a3 += bh(uu[k].y);
                a4 += bl(uu[k].z); a5 += bh(uu[k].z);
                a6 += bl(uu[k].w); a7 += bh(uu[k].w);
            }
        }
        e += 8;
    }
    float di = dinv[node];
    if (c4 < 6){
        float4 bz0 = *(const float4*)&bias[8*c4];
        float4 bz1 = *(const float4*)&bias[8*c4 + 4];
        a0 = fmaxf(a0*di + bz0.x, 0.f); a1 = fmaxf(a1*di + bz0.y, 0.f);
        a2 = fmaxf(a2*di + bz0.z, 0.f); a3 = fmaxf(a3*di + bz0.w, 0.f);
        a4 = fmaxf(a4*di + bz1.x, 0.f); a5 = fmaxf(a5*di + bz1.y, 0.f);
        a6 = fmaxf(a6*di + bz1.z, 0.f); a7 = fmaxf(a7*di + bz1.w, 0.f);
        uint4 w;
        w.x = pk(a0,a1); w.y = pk(a2,a3); w.z = pk(a4,a5); w.w = pk(a6,a7);
        *(uint4*)&out[(size_t)node*48 + c4*8] = w;
    }
}

// ---------------- fused MLP head: 32 graphs/block, g1 in LDS, l2/l3 fused ----------------

__global__ __launch_bounds__(256) void k_head(
    const u16* __restrict__ A,      // agg2, graph rows [8192][1920] bf16
    const u16* __restrict__ l1wt,   // [256][1920]
    const float* __restrict__ l1b,
    const u16* __restrict__ l2wt,   // [64][256]
    const float* __restrict__ l2b,
    const float* __restrict__ l3w, const float* __restrict__ l3b,
    float* __restrict__ out)
{
    __shared__ __align__(16) u16 As[32][72];
    __shared__ __align__(16) u16 Bt[256][72];
    __shared__ float part[32][2];
    u16 (*sh1)[264] = (u16(*)[264])&Bt[0][0];
    const int tid = threadIdx.x;
    const int g0 = blockIdx.x*32;
    const int w = tid >> 6, l = tid & 63;
    const int lr = l & 15, lg = l >> 4;
    const int r0 = (w & 1)*16;
    const int c0 = (w >> 1)*128;
    f32x4 acc[8] = {};
    for (int k0 = 0; k0 < 1920; k0 += 64){
        __syncthreads();
        {
            int r = tid >> 3, s = tid & 7;
            *(uint4*)&As[r][s*8] = *(const uint4*)&A[(size_t)(g0+r)*1920 + k0 + s*8];
        }
        for (int i = tid; i < 2048; i += 256){
            int n = i >> 3, s = i & 7;
            *(uint4*)&Bt[n][s*8] = *(const uint4*)&l1wt[(size_t)n*1920 + k0 + s*8];
        }
        __syncthreads();
        #pragma unroll
        for (int s = 0; s < 2; ++s){
            s16x8 af = *(const s16x8*)&As[r0+lr][s*32 + lg*8];
            #pragma unroll
            for (int t = 0; t < 8; ++t){
                s16x8 bf = *(const s16x8*)&Bt[c0 + t*16 + lr][s*32 + lg*8];
                acc[t] = __builtin_amdgcn_mfma_f32_16x16x32_bf16(af, bf, acc[t], 0, 0, 0);
            }
        }
    }
    __syncthreads();   // everyone done reading Bt before overlay write
    #pragma unroll
    for (int t = 0; t < 8; ++t){
        int col = c0 + t*16 + lr;
        float bs = l1b[col];
        #pragma unroll
        for (int r = 0; r < 4; ++r)
            sh1[r0 + lg*4 + r][col] = f2b(fmaxf(acc[t][r] + bs, 0.f));
    }
    __syncthreads();
    f32x4 acc2[2] = {};
    #pragma unroll
    for (int s = 0; s < 8; ++s){
        s16x8 af = *(const s16x8*)&sh1[r0+lr][s*32 + lg*8];
        #pragma unroll
        for (int t = 0; t < 2; ++t){
            int col = (w>>1)*32 + t*16 + lr;
            s16x8 bf = *(const s16x8*)&l2wt[(size_t)col*256 + s*32 + lg*8];
            acc2[t] = __builtin_amdgcn_mfma_f32_16x16x32_bf16(af, bf, acc2[t], 0, 0, 0);
        }
    }
    float p[4];
    #pragma unroll
    for (int r = 0; r < 4; ++r){
        p[r] = 0.f;
        #pragma unroll
        for (int t = 0; t < 2; ++t){
            int col = (w>>1)*32 + t*16 + lr;
            p[r] += fmaxf(acc2[t][r] + l2b[col], 0.f) * l3w[col];
        }
    }
    #pragma unroll
    for (int o = 1; o < 16; o <<= 1){
        #pragma unroll
        for (int r = 0; r < 4; ++r) p[r] += __shfl_xor(p[r], o);
    }
    if (lr == 0){
        #pragma unroll
        for (int r = 0; r < 4; ++r)
            part[r0 + lg*4 + r][w>>1] = p[r];
    }
    __syncthreads();
    if (tid < 32)
        out[g0 + tid] = 1.0f / (1.0f + expf(-(part[tid][0] + part[tid][1] + l3b[0])));
}

extern "C" void kernel_launch(void* const* d_in, const int* in_sizes, int n_in,
                              void* d_out, int out_size, void* d_ws, size_t ws_size,
                              hipStream_t stream){
    const float* x   = (const float*)d_in[0];
    const int*   ei  = (const int*)  d_in[1];
    const int*   src = ei;
    const int*   dst = ei + N_EDGES;
    const float* W1  = (const float*)d_in[2];
    const float* b1  = (const float*)d_in[3];
    const float* W2  = (const float*)d_in[4];
    const float* b2  = (const float*)d_in[5];
    const float* l1w = (const float*)d_in[6];
    const float* l1b = (const float*)d_in[7];
    const float* l2w = (const float*)d_in[8];
    const float* l2b = (const float*)d_in[9];
    const float* l3w = (const float*)d_in[10];
    const float* l3b = (const float*)d_in[11];
    float* out = (float*)d_out;

    char* w = (char*)d_ws;
    auto alloc = [&](size_t bytes){ void* p = (void*)w; w += (bytes + 255) & ~(size_t)255; return p; };
    float* dinv    = (float*)alloc((size_t)N_NODES*4);
    int*   rowst   = (int*)  alloc((size_t)N_NODES*4);
    int*   rend    = (int*)  alloc((size_t)N_NODES*4);
    int*   perm    = (int*)  alloc((size_t)N_NODES*4);
    int*   gcur    = (int*)  alloc(NB*4);
    u16*   w1t     = (u16*)  alloc(96*64*2);
    u16*   w2t     = (u16*)  alloc(48*96*2);
    u16*   l1wt    = (u16*)  alloc((size_t)256*1920*2);
    u16*   l2wt    = (u16*)  alloc((size_t)64*256*2);
    int*   csr     = (int*)  alloc((size_t)NB*BCAPE*4);
    uint*  staging = (uint*) alloc((size_t)NB*BCAPE*4);
    char*  BUF_P   = (char*) alloc((size_t)N_NODES*32*4);   // xs32 -> ts (both 42MB)
    char*  BUF_Q   = (char*) alloc((size_t)N_NODES*64*2);   // agg1 -> agg2

    uint* xs32 = (uint*)BUF_P;          // [bucket .. gather1]
    u16*  ts   = (u16*) BUF_P;          // [conv_mlp .. gather2], [N][64]
    u16*  agg1 = (u16*) BUF_Q;          // [gather1 .. conv_mlp]
    u16*  agg2 = (u16*) BUF_Q;          // [gather2 .. head], dense [N][48]

    // prep: weight transposes + gcur zero (one launch)
    k_prep     <<<129, 256, 0, stream>>>(W1, W2, l1w, l2w, w1t, w2t, l1wt, l2wt, gcur);

    // bucketed CSR build (fixed-cap buckets) + fused x prescale
    k_partition<<<640, 256, 0, stream>>>(src, dst, gcur, staging);
    k_bucket   <<<640, 512, 0, stream>>>(staging, gcur, x, rowst, rend, dinv, csr, perm, xs32);

    // conv1: gather -> MFMA conv (padded-64 prescaled output)
    k_gather1  <<<10240, 256, 0, stream>>>(rowst, rend, csr, dinv, perm,
                                           (const uint4*)xs32, agg1);
    k_conv_mlp <<<5120,  256, 0, stream>>>(agg1, w1t, b1, w2t, dinv, ts);

    // conv2: gather (uint4 from padded-64) + bias + relu -> dense-48 agg2
    k_gather2  <<<10240, 256, 0, stream>>>(rowst, rend, csr, dinv, perm,
                                           (const uint4*)ts, b2, agg2);

    // fused MLP head
    k_head     <<<256, 256, 0, stream>>>(agg2, l1wt, l1b, l2wt, l2b, l3w, l3b, out);
}

// Round 11
// 337.292 us; speedup vs baseline: 1.0716x; 1.0062x over previous
//
#include <hip/hip_runtime.h>

#define N_NODES 327680
#define N_EDGES 2621440
#define NGRAPH  8192
#define NB      640          // dst buckets (512 nodes each)
#define BCAPE   4608         // fixed per-bucket capacity (mean 4096, +8 sigma)

typedef unsigned int uint;
typedef unsigned short u16;
typedef __attribute__((ext_vector_type(8))) short s16x8;
typedef __attribute__((ext_vector_type(4))) float f32x4;

__device__ __forceinline__ float bl(uint u){ return __uint_as_float(u << 16); }
__device__ __forceinline__ float bh(uint u){ return __uint_as_float(u & 0xffff0000u); }
__device__ __forceinline__ u16 f2b(float f){
    uint u = __float_as_uint(f);
    u += 0x7fffu + ((u>>16)&1u);          // round-to-nearest-even
    return (u16)(u>>16);
}
__device__ __forceinline__ uint pk(float a, float b){
    return (uint)f2b(a) | ((uint)f2b(b) << 16);
}

// ---------------- prep: weight transposes (bf16) + gcur zero, one launch ----------------

__device__ void tr_tile(const float* __restrict__ in, u16* __restrict__ out,
                        int K, int N, int Kpad, int kb, int nb){
    __shared__ u16 t[64][72];
    for (int i = threadIdx.x; i < 4096; i += 256){
        int k = i >> 6, n = i & 63;
        int gk = kb + k, gn = nb + n;
        float v = (gk < K && gn < N) ? in[(size_t)gk*N + gn] : 0.f;
        t[n][k] = f2b(v);
    }
    __syncthreads();
    for (int i = threadIdx.x; i < 4096; i += 256){
        int n = i >> 6, k = i & 63;
        int gk = kb + k, gn = nb + n;
        if (gn < N && gk < Kpad) out[(size_t)gn*Kpad + gk] = t[n][k];
    }
}

__global__ __launch_bounds__(256) void k_prep(
    const float* __restrict__ W1, const float* __restrict__ W2,
    const float* __restrict__ l1w, const float* __restrict__ l2w,
    u16* __restrict__ w1t, u16* __restrict__ w2t,
    u16* __restrict__ l1wt, u16* __restrict__ l2wt, int* __restrict__ gcur)
{
    int b = blockIdx.x;
    if (b < 120)      tr_tile(l1w, l1wt, 1920, 256, 1920, (b%30)*64, (b/30)*64);
    else if (b < 124) tr_tile(l2w, l2wt, 256,  64,  256,  (b-120)*64, 0);
    else if (b < 126) tr_tile(W1,  w1t,  58,   96,  64,   0, (b-124)*64);
    else if (b < 128) tr_tile(W2,  w2t,  96,   48,  96,   (b-126)*64, 0);
    else {
        for (int i = threadIdx.x; i < NB; i += 256) gcur[i] = 0;
    }
}

// ---------------- partition edges into fixed-cap dst-buckets (packed uint) ----------------

__global__ __launch_bounds__(256) void k_partition(
    const int* __restrict__ src, const int* __restrict__ dst,
    int* __restrict__ gcur, uint* __restrict__ staging)
{
    __shared__ int cnt[NB], base_[NB];
    int tid = threadIdx.x;
    for (int i = tid; i < NB; i += 256) cnt[i] = 0;
    __syncthreads();
    int e0 = blockIdx.x*4096;
    int d[16];
    #pragma unroll
    for (int j = 0; j < 16; ++j){
        d[j] = dst[e0 + j*256 + tid];
        atomicAdd(&cnt[d[j] >> 9], 1);
    }
    __syncthreads();
    for (int i = tid; i < NB; i += 256)
        base_[i] = atomicAdd(&gcur[i], cnt[i]);
    __syncthreads();
    for (int i = tid; i < NB; i += 256) cnt[i] = 0;
    __syncthreads();
    #pragma unroll
    for (int j = 0; j < 16; ++j){
        int e = e0 + j*256 + tid;
        int b = d[j] >> 9;
        int r = atomicAdd(&cnt[b], 1);
        staging[(uint)b*BCAPE + base_[b] + r] = (uint)src[e] | ((uint)(d[j] & 511) << 19);
    }
}

// ---- per-bucket: degree, dinv, row starts, csr place, degree-sorted perm, x prescale ----

__global__ __launch_bounds__(512) void k_bucket(
    const uint* __restrict__ staging, const int* __restrict__ gcur,
    const float* __restrict__ x,
    int* __restrict__ rowst, int* __restrict__ rendg, float* __restrict__ dinvg,
    int* __restrict__ csr, int* __restrict__ perm, uint* __restrict__ xs32)
{
    __shared__ uint sedge[BCAPE];
    __shared__ int deg[512];
    __shared__ int cur[512];
    __shared__ int wsum[8];
    __shared__ int dh[64], dbase[64];
    __shared__ float sdinv[512];
    const int b = blockIdx.x;
    const int tid = threadIdx.x;
    const int lo = b*BCAPE;
    int cnt = gcur[b];
    if (cnt > BCAPE) cnt = BCAPE;   // safety (8-sigma margin, never expected)
    deg[tid] = 0;
    if (tid < 64) dh[tid] = 0;
    __syncthreads();
    for (int t = tid; t < cnt; t += 512){
        uint ed = staging[lo + t];
        sedge[t] = ed;
        atomicAdd(&deg[ed >> 19], 1);
    }
    __syncthreads();
    int d = deg[tid];
    // wave-level inclusive scan (64 lanes), then cross-wave prefix
    int incl = d;
    #pragma unroll
    for (int o = 1; o < 64; o <<= 1){
        int t = __shfl_up(incl, o);
        if ((tid & 63) >= o) incl += t;
    }
    if ((tid & 63) == 63) wsum[tid >> 6] = incl;
    __syncthreads();
    if (tid == 0){
        int a = 0;
        #pragma unroll
        for (int i = 0; i < 8; ++i){ int v = wsum[i]; wsum[i] = a; a += v; }
    }
    __syncthreads();
    incl += wsum[tid >> 6];
    int excl = incl - d;
    int gnode = b*512 + tid;
    float dv = 1.0f / sqrtf((float)(d + 1));
    rowst[gnode] = lo + excl;
    rendg[gnode] = lo + incl;
    dinvg[gnode] = dv;
    sdinv[tid] = dv;
    cur[tid] = lo + excl;
    int bin = min(d, 63);
    atomicAdd(&dh[bin], 1);
    __syncthreads();
    if (tid == 0){
        int a = 0;
        #pragma unroll
        for (int i = 0; i < 64; ++i){ dbase[i] = a; a += dh[i]; dh[i] = 0; }
    }
    __syncthreads();
    int pos = dbase[bin] + atomicAdd(&dh[bin], 1);
    perm[b*512 + pos] = gnode;
    for (int t = tid; t < cnt; t += 512){
        uint ed = sedge[t];
        int p = atomicAdd(&cur[ed >> 19], 1);
        csr[p] = (int)(ed & 0x7FFFFu);
    }
    // prescale this bucket's 512 nodes: xs[node][32] = pk(x*dinv), pad cols>=58
    const size_t n0 = (size_t)b*512;
    for (int i = tid; i < 512*32; i += 512){
        int n = i >> 5, c = i & 31;
        float dvn = sdinv[n];
        float a = 0.f, bb = 0.f;
        if (c < 29){
            float2 v = *(const float2*)&x[(n0 + n)*58 + 2*c];
            a = v.x * dvn; bb = v.y * dvn;
        }
        xs32[(n0 + n)*32 + c] = pk(a, bb);
    }
}

// ---- conv1 gather: 8 lanes/node x uint4 (16B), 8 edges batched, degree-sorted perm ----

__global__ __launch_bounds__(256) void k_gather1(
    const int* __restrict__ rs, const int* __restrict__ re,
    const int* __restrict__ csr, const float* __restrict__ dinv,
    const int* __restrict__ perm,
    const uint4* __restrict__ feat4,   // xs [N] rows of 128B packed bf16
    u16* __restrict__ out)             // agg1 [N][64]
{
    int slot = (blockIdx.x*256 + threadIdx.x) >> 3;
    int c4 = threadIdx.x & 7;
    int node = perm[slot];
    uint4 u = feat4[((uint)node << 3) + c4];
    float a0 = bl(u.x), a1 = bh(u.x), a2 = bl(u.y), a3 = bh(u.y);
    float a4 = bl(u.z), a5 = bh(u.z), a6 = bl(u.w), a7 = bh(u.w);
    int e = rs[node];
    const int e1 = re[node];
    while (e < e1){
        const int last = e1 - 1;
        int idx[8];
        #pragma unroll
        for (int k = 0; k < 8; ++k) idx[k] = csr[min(e + k, last)];
        uint4 uu[8];
        #pragma unroll
        for (int k = 0; k < 8; ++k) uu[k] = feat4[((uint)idx[k] << 3) + c4];
        #pragma unroll
        for (int k = 0; k < 8; ++k){
            if (e + k < e1){
                a0 += bl(uu[k].x); a1 += bh(uu[k].x);
                a2 += bl(uu[k].y); a3 += bh(uu[k].y);
                a4 += bl(uu[k].z); a5 += bh(uu[k].z);
                a6 += bl(uu[k].w); a7 += bh(uu[k].w);
            }
        }
        e += 8;
    }
    float di = dinv[node];
    a0 *= di; a1 *= di; a2 *= di; a3 *= di;
    a4 *= di; a5 *= di; a6 *= di; a7 *= di;
    uint4 w;
    w.x = pk(a0,a1); w.y = pk(a2,a3); w.z = pk(a4,a5); w.w = pk(a6,a7);
    *(uint4*)&out[(size_t)node*64 + c4*8] = w;
}

// ---- conv MLP: ts = (relu(agg1 @ W1 + b1) @ W2) * dinv  (MFMA, 128 rows/block) ----

__global__ __launch_bounds__(512) void k_conv_mlp(
    const u16* __restrict__ A,      // agg1 [N][64] (58 real cols, rest 0)
    const u16* __restrict__ w1t,    // [96][64] bf16 (transposed, k-padded)
    const float* __restrict__ b1,   // [96]
    const u16* __restrict__ w2t,    // [48][96] bf16 (transposed)
    const float* __restrict__ dinv,
    u16* __restrict__ ts)           // [N][64], cols>=48 zeroed (prescaled by dinv)
{
    __shared__ __align__(16) u16 As[128][72];
    __shared__ __align__(16) u16 Bt1[96][72];
    __shared__ __align__(16) u16 Bt2[48][104];
    __shared__ __align__(16) u16 sh1[128][104];
    __shared__ float sb1[96];
    const int tid = threadIdx.x;
    {
        const u16* Ab = A + (size_t)blockIdx.x*128*64;
        for (int i = tid; i < 1024; i += 512){
            int r = i >> 3, s = i & 7;
            *(uint4*)&As[r][s*8] = *(const uint4*)&Ab[r*64 + s*8];
        }
    }
    for (int i = tid; i < 768; i += 512){
        int n = i >> 3, s = i & 7;
        *(uint4*)&Bt1[n][s*8] = *(const uint4*)&w1t[n*64 + s*8];
    }
    for (int i = tid; i < 576; i += 512){
        int n = i / 12, s = i % 12;
        *(uint4*)&Bt2[n][s*8] = *(const uint4*)&w2t[n*96 + s*8];
    }
    if (tid < 96) sb1[tid] = b1[tid];
    __syncthreads();

    const int wv = tid >> 6, l = tid & 63;
    const int lr = l & 15, lg = l >> 4;
    const int r0 = wv*16;              // 8 waves x 16 rows = 128 rows

    f32x4 acc1[6] = {};
    #pragma unroll
    for (int s = 0; s < 2; ++s){
        s16x8 af = *(const s16x8*)&As[r0+lr][s*32 + lg*8];
        #pragma unroll
        for (int t = 0; t < 6; ++t){
            s16x8 bf = *(const s16x8*)&Bt1[t*16+lr][s*32 + lg*8];
            acc1[t] = __builtin_amdgcn_mfma_f32_16x16x32_bf16(af, bf, acc1[t], 0, 0, 0);
        }
    }
    #pragma unroll
    for (int t = 0; t < 6; ++t){
        int col = t*16 + lr;
        float bias = sb1[col];
        #pragma unroll
        for (int r = 0; r < 4; ++r)
            sh1[r0 + lg*4 + r][col] = f2b(fmaxf(acc1[t][r] + bias, 0.f));
    }
    __syncthreads();

    f32x4 acc2[3] = {};
    #pragma unroll
    for (int s = 0; s < 3; ++s){
        s16x8 af = *(const s16x8*)&sh1[r0+lr][s*32 + lg*8];
        #pragma unroll
        for (int t = 0; t < 3; ++t){
            s16x8 bf = *(const s16x8*)&Bt2[t*16+lr][s*32 + lg*8];
            acc2[t] = __builtin_amdgcn_mfma_f32_16x16x32_bf16(af, bf, acc2[t], 0, 0, 0);
        }
    }
    size_t gbase = (size_t)blockIdx.x*128;
    #pragma unroll
    for (int r = 0; r < 4; ++r){
        size_t row = gbase + r0 + lg*4 + r;
        float dv = dinv[row];
        #pragma unroll
        for (int t = 0; t < 3; ++t)
            ts[row*64 + t*16 + lr] = f2b(acc2[t][r] * dv);
        ts[row*64 + 48 + lr] = 0;
    }
}

// ---- conv2 gather: 8 lanes/node x uint4 from padded-64 ts, dense-48 masked write ----

__global__ __launch_bounds__(256) void k_gather2(
    const int* __restrict__ rs, const int* __restrict__ re,
    const int* __restrict__ csr, const float* __restrict__ dinv,
    const int* __restrict__ perm,
    const uint4* __restrict__ feat4,   // ts [N] rows of 128B packed bf16 (48 real)
    const float* __restrict__ bias,
    u16* __restrict__ out)             // agg2 dense [N][48]
{
    int slot = (blockIdx.x*256 + threadIdx.x) >> 3;
    int c4 = threadIdx.x & 7;
    int node = perm[slot];
    uint4 u = feat4[((uint)node << 3) + c4];
    float a0 = bl(u.x), a1 = bh(u.x), a2 = bl(u.y), a3 = bh(u.y);
    float a4 = bl(u.z), a5 = bh(u.z), a6 = bl(u.w), a7 = bh(u.w);
    int e = rs[node];
    const int e1 = re[node];
    while (e < e1){
        const int last = e1 - 1;
        int idx[8];
        #pragma unroll
        for (int k = 0; k < 8; ++k) idx[k] = csr[min(e + k, last)];
        uint4 uu[8];
        #pragma unroll
        for (int k = 0; k < 8; ++k) uu[k] = feat4[((uint)idx[k] << 3) + c4];
        #pragma unroll
        for (int k = 0; k < 8; ++k){
            if (e + k < e1){
                a0 += bl(uu[k].x); a1 += bh(uu[k].x);
                a2 += bl(uu[k].y); a3 += bh(uu[k].y);
                a4 += bl(uu[k].z); a5 += bh(uu[k].z);
                a6 += bl(uu[k].w); a7 += bh(uu[k].w);
            }
        }
        e += 8;
    }
    float di = dinv[node];
    if (c4 < 6){
        float4 bz0 = *(const float4*)&bias[8*c4];
        float4 bz1 = *(const float4*)&bias[8*c4 + 4];
        a0 = fmaxf(a0*di + bz0.x, 0.f); a1 = fmaxf(a1*di + bz0.y, 0.f);
        a2 = fmaxf(a2*di + bz0.z, 0.f); a3 = fmaxf(a3*di + bz0.w, 0.f);
        a4 = fmaxf(a4*di + bz1.x, 0.f); a5 = fmaxf(a5*di + bz1.y, 0.f);
        a6 = fmaxf(a6*di + bz1.z, 0.f); a7 = fmaxf(a7*di + bz1.w, 0.f);
        uint4 w;
        w.x = pk(a0,a1); w.y = pk(a2,a3); w.z = pk(a4,a5); w.w = pk(a6,a7);
        *(uint4*)&out[(size_t)node*48 + c4*8] = w;
    }
}

// ---- fused MLP head: 32 graphs/block, 512 threads (8 waves), g1 in LDS, l2/l3 fused ----

__global__ __launch_bounds__(512) void k_head(
    const u16* __restrict__ A,      // agg2, graph rows [8192][1920] bf16
    const u16* __restrict__ l1wt,   // [256][1920]
    const float* __restrict__ l1b,
    const u16* __restrict__ l2wt,   // [64][256]
    const float* __restrict__ l2b,
    const float* __restrict__ l3w, const float* __restrict__ l3b,
    float* __restrict__ out)
{
    __shared__ __align__(16) u16 As[32][72];
    __shared__ __align__(16) u16 Bt[256][72];
    __shared__ float part[32][4];
    u16 (*sh1)[264] = (u16(*)[264])&Bt[0][0];
    const int tid = threadIdx.x;
    const int g0 = blockIdx.x*32;
    const int w = tid >> 6, l = tid & 63;
    const int lr = l & 15, lg = l >> 4;
    const int r0 = (w & 1)*16;         // 2 row-halves
    const int c0 = (w >> 1)*64;        // 4 col-quarters of 256
    f32x4 acc[4] = {};
    for (int k0 = 0; k0 < 1920; k0 += 64){
        __syncthreads();
        if (tid < 256){
            int r = tid >> 3, s = tid & 7;
            *(uint4*)&As[r][s*8] = *(const uint4*)&A[(size_t)(g0+r)*1920 + k0 + s*8];
        }
        for (int i = tid; i < 2048; i += 512){
            int n = i >> 3, s = i & 7;
            *(uint4*)&Bt[n][s*8] = *(const uint4*)&l1wt[(size_t)n*1920 + k0 + s*8];
        }
        __syncthreads();
        #pragma unroll
        for (int s = 0; s < 2; ++s){
            s16x8 af = *(const s16x8*)&As[r0+lr][s*32 + lg*8];
            #pragma unroll
            for (int t = 0; t < 4; ++t){
                s16x8 bf = *(const s16x8*)&Bt[c0 + t*16 + lr][s*32 + lg*8];
                acc[t] = __builtin_amdgcn_mfma_f32_16x16x32_bf16(af, bf, acc[t], 0, 0, 0);
            }
        }
    }
    __syncthreads();   // everyone done reading Bt before overlay write
    #pragma unroll
    for (int t = 0; t < 4; ++t){
        int col = c0 + t*16 + lr;
        float bs = l1b[col];
        #pragma unroll
        for (int r = 0; r < 4; ++r)
            sh1[r0 + lg*4 + r][col] = f2b(fmaxf(acc[t][r] + bs, 0.f));
    }
    __syncthreads();
    // l2: each wave computes 16 output cols for its 16 rows
    f32x4 acc2 = {};
    const int col = (w >> 1)*16 + lr;
    #pragma unroll
    for (int s = 0; s < 8; ++s){
        s16x8 af = *(const s16x8*)&sh1[r0+lr][s*32 + lg*8];
        s16x8 bf = *(const s16x8*)&l2wt[(size_t)col*256 + s*32 + lg*8];
        acc2 = __builtin_amdgcn_mfma_f32_16x16x32_bf16(af, bf, acc2, 0, 0, 0);
    }
    float lb = l2b[col], lw = l3w[col];
    float p[4];
    #pragma unroll
    for (int r = 0; r < 4; ++r)
        p[r] = fmaxf(acc2[r] + lb, 0.f) * lw;
    #pragma unroll
    for (int o = 1; o < 16; o <<= 1){
        #pragma unroll
        for (int r = 0; r < 4; ++r) p[r] += __shfl_xor(p[r], o);
    }
    if (lr == 0){
        #pragma unroll
        for (int r = 0; r < 4; ++r)
            part[r0 + lg*4 + r][w>>1] = p[r];
    }
    __syncthreads();
    if (tid < 32)
        out[g0 + tid] = 1.0f / (1.0f + expf(-(part[tid][0] + part[tid][1]
                                            + part[tid][2] + part[tid][3] + l3b[0])));
}

extern "C" void kernel_launch(void* const* d_in, const int* in_sizes, int n_in,
                              void* d_out, int out_size, void* d_ws, size_t ws_size,
                              hipStream_t stream){
    const float* x   = (const float*)d_in[0];
    const int*   ei  = (const int*)  d_in[1];
    const int*   src = ei;
    const int*   dst = ei + N_EDGES;
    const float* W1  = (const float*)d_in[2];
    const float* b1  = (const float*)d_in[3];
    const float* W2  = (const float*)d_in[4];
    const float* b2  = (const float*)d_in[5];
    const float* l1w = (const float*)d_in[6];
    const float* l1b = (const float*)d_in[7];
    const float* l2w = (const float*)d_in[8];
    const float* l2b = (const float*)d_in[9];
    const float* l3w = (const float*)d_in[10];
    const float* l3b = (const float*)d_in[11];
    float* out = (float*)d_out;

    char* w = (char*)d_ws;
    auto alloc = [&](size_t bytes){ void* p = (void*)w; w += (bytes + 255) & ~(size_t)255; return p; };
    float* dinv    = (float*)alloc((size_t)N_NODES*4);
    int*   rowst   = (int*)  alloc((size_t)N_NODES*4);
    int*   rend    = (int*)  alloc((size_t)N_NODES*4);
    int*   perm    = (int*)  alloc((size_t)N_NODES*4);
    int*   gcur    = (int*)  alloc(NB*4);
    u16*   w1t     = (u16*)  alloc(96*64*2);
    u16*   w2t     = (u16*)  alloc(48*96*2);
    u16*   l1wt    = (u16*)  alloc((size_t)256*1920*2);
    u16*   l2wt    = (u16*)  alloc((size_t)64*256*2);
    int*   csr     = (int*)  alloc((size_t)NB*BCAPE*4);
    uint*  staging = (uint*) alloc((size_t)NB*BCAPE*4);
    char*  BUF_P   = (char*) alloc((size_t)N_NODES*32*4);   // xs32 -> ts (both 42MB)
    char*  BUF_Q   = (char*) alloc((size_t)N_NODES*64*2);   // agg1 -> agg2

    uint* xs32 = (uint*)BUF_P;          // [bucket .. gather1]
    u16*  ts   = (u16*) BUF_P;          // [conv_mlp .. gather2], [N][64]
    u16*  agg1 = (u16*) BUF_Q;          // [gather1 .. conv_mlp]
    u16*  agg2 = (u16*) BUF_Q;          // [gather2 .. head], dense [N][48]

    // prep: weight transposes + gcur zero (one launch)
    k_prep     <<<129, 256, 0, stream>>>(W1, W2, l1w, l2w, w1t, w2t, l1wt, l2wt, gcur);

    // bucketed CSR build (fixed-cap buckets) + fused x prescale
    k_partition<<<640, 256, 0, stream>>>(src, dst, gcur, staging);
    k_bucket   <<<640, 512, 0, stream>>>(staging, gcur, x, rowst, rend, dinv, csr, perm, xs32);

    // conv1: gather -> MFMA conv (padded-64 prescaled output)
    k_gather1  <<<10240, 256, 0, stream>>>(rowst, rend, csr, dinv, perm,
                                           (const uint4*)xs32, agg1);
    k_conv_mlp <<<2560,  512, 0, stream>>>(agg1, w1t, b1, w2t, dinv, ts);

    // conv2: gather (uint4 from padded-64) + bias + relu -> dense-48 agg2
    k_gather2  <<<10240, 256, 0, stream>>>(rowst, rend, csr, dinv, perm,
                                           (const uint4*)ts, b2, agg2);

    // fused MLP head
    k_head     <<<256, 512, 0, stream>>>(agg2, l1wt, l1b, l2wt, l2b, l3w, l3b, out);
}

// Round 12
// 321.023 us; speedup vs baseline: 1.1259x; 1.0507x over previous
//
#include <hip/hip_runtime.h>

#define N_NODES 327680
#define N_EDGES 2621440
#define NGRAPH  8192
#define NB      640          // dst buckets (512 nodes each)
#define BCAPE   4608         // fixed per-bucket capacity (mean 4096, +8 sigma)

typedef unsigned int uint;
typedef unsigned short u16;
typedef __attribute__((ext_vector_type(8))) short s16x8;
typedef __attribute__((ext_vector_type(4))) float f32x4;
typedef __attribute__((ext_vector_type(2))) float f32x2;

__device__ __forceinline__ float bl(uint u){ return __uint_as_float(u << 16); }
__device__ __forceinline__ float bh(uint u){ return __uint_as_float(u & 0xffff0000u); }
__device__ __forceinline__ u16 f2b(float f){
    uint u = __float_as_uint(f);
    u += 0x7fffu + ((u>>16)&1u);          // round-to-nearest-even
    return (u16)(u>>16);
}
__device__ __forceinline__ uint pk(float a, float b){
    return (uint)f2b(a) | ((uint)f2b(b) << 16);
}
// fp8 e4m3 HW converts (gfx950)
__device__ __forceinline__ f32x2 f8lo(uint w){ return __builtin_amdgcn_cvt_pk_f32_fp8((int)w, false); }
__device__ __forceinline__ f32x2 f8hi(uint w){ return __builtin_amdgcn_cvt_pk_f32_fp8((int)w, true); }
__device__ __forceinline__ uint pk4f8(float a, float b, float c, float d){
    int w = __builtin_amdgcn_cvt_pk_fp8_f32(a, b, 0, false);
    w = __builtin_amdgcn_cvt_pk_fp8_f32(c, d, w, true);
    return (uint)w;
}

// ---------------- prep: weight transposes (bf16) + gcur zero, one launch ----------------

__device__ void tr_tile(const float* __restrict__ in, u16* __restrict__ out,
                        int K, int N, int Kpad, int kb, int nb){
    __shared__ u16 t[64][72];
    for (int i = threadIdx.x; i < 4096; i += 256){
        int k = i >> 6, n = i & 63;
        int gk = kb + k, gn = nb + n;
        float v = (gk < K && gn < N) ? in[(size_t)gk*N + gn] : 0.f;
        t[n][k] = f2b(v);
    }
    __syncthreads();
    for (int i = threadIdx.x; i < 4096; i += 256){
        int n = i >> 6, k = i & 63;
        int gk = kb + k, gn = nb + n;
        if (gn < N && gk < Kpad) out[(size_t)gn*Kpad + gk] = t[n][k];
    }
}

__global__ __launch_bounds__(256) void k_prep(
    const float* __restrict__ W1, const float* __restrict__ W2,
    const float* __restrict__ l1w, const float* __restrict__ l2w,
    u16* __restrict__ w1t, u16* __restrict__ w2t,
    u16* __restrict__ l1wt, u16* __restrict__ l2wt, int* __restrict__ gcur)
{
    int b = blockIdx.x;
    if (b < 120)      tr_tile(l1w, l1wt, 1920, 256, 1920, (b%30)*64, (b/30)*64);
    else if (b < 124) tr_tile(l2w, l2wt, 256,  64,  256,  (b-120)*64, 0);
    else if (b < 126) tr_tile(W1,  w1t,  58,   96,  64,   0, (b-124)*64);
    else if (b < 128) tr_tile(W2,  w2t,  96,   48,  96,   (b-126)*64, 0);
    else {
        for (int i = threadIdx.x; i < NB; i += 256) gcur[i] = 0;
    }
}

// ---------------- partition edges into fixed-cap dst-buckets (packed uint) ----------------

__global__ __launch_bounds__(256) void k_partition(
    const int* __restrict__ src, const int* __restrict__ dst,
    int* __restrict__ gcur, uint* __restrict__ staging)
{
    __shared__ int cnt[NB], base_[NB];
    int tid = threadIdx.x;
    for (int i = tid; i < NB; i += 256) cnt[i] = 0;
    __syncthreads();
    int e0 = blockIdx.x*4096;
    int d[16];
    #pragma unroll
    for (int j = 0; j < 16; ++j){
        d[j] = dst[e0 + j*256 + tid];
        atomicAdd(&cnt[d[j] >> 9], 1);
    }
    __syncthreads();
    for (int i = tid; i < NB; i += 256)
        base_[i] = atomicAdd(&gcur[i], cnt[i]);
    __syncthreads();
    for (int i = tid; i < NB; i += 256) cnt[i] = 0;
    __syncthreads();
    #pragma unroll
    for (int j = 0; j < 16; ++j){
        int e = e0 + j*256 + tid;
        int b = d[j] >> 9;
        int r = atomicAdd(&cnt[b], 1);
        staging[(uint)b*BCAPE + base_[b] + r] = (uint)src[e] | ((uint)(d[j] & 511) << 19);
    }
}

// ---- per-bucket: degree, dinv, row starts, csr place, degree-sorted perm, x prescale(fp8) ----

__global__ __launch_bounds__(512) void k_bucket(
    const uint* __restrict__ staging, const int* __restrict__ gcur,
    const float* __restrict__ x,
    int* __restrict__ rowst, int* __restrict__ rendg, float* __restrict__ dinvg,
    int* __restrict__ csr, int* __restrict__ perm, uint* __restrict__ xs32)
{
    __shared__ uint sedge[BCAPE];
    __shared__ int deg[512];
    __shared__ int cur[512];
    __shared__ int wsum[8];
    __shared__ int dh[64], dbase[64];
    __shared__ float sdinv[512];
    const int b = blockIdx.x;
    const int tid = threadIdx.x;
    const int lo = b*BCAPE;
    int cnt = gcur[b];
    if (cnt > BCAPE) cnt = BCAPE;   // safety (8-sigma margin, never expected)
    deg[tid] = 0;
    if (tid < 64) dh[tid] = 0;
    __syncthreads();
    for (int t = tid; t < cnt; t += 512){
        uint ed = staging[lo + t];
        sedge[t] = ed;
        atomicAdd(&deg[ed >> 19], 1);
    }
    __syncthreads();
    int d = deg[tid];
    // wave-level inclusive scan (64 lanes), then cross-wave prefix
    int incl = d;
    #pragma unroll
    for (int o = 1; o < 64; o <<= 1){
        int t = __shfl_up(incl, o);
        if ((tid & 63) >= o) incl += t;
    }
    if ((tid & 63) == 63) wsum[tid >> 6] = incl;
    __syncthreads();
    if (tid == 0){
        int a = 0;
        #pragma unroll
        for (int i = 0; i < 8; ++i){ int v = wsum[i]; wsum[i] = a; a += v; }
    }
    __syncthreads();
    incl += wsum[tid >> 6];
    int excl = incl - d;
    int gnode = b*512 + tid;
    float dv = 1.0f / sqrtf((float)(d + 1));
    rowst[gnode] = lo + excl;
    rendg[gnode] = lo + incl;
    dinvg[gnode] = dv;
    sdinv[tid] = dv;
    cur[tid] = lo + excl;
    int bin = min(d, 63);
    atomicAdd(&dh[bin], 1);
    __syncthreads();
    if (tid == 0){
        int a = 0;
        #pragma unroll
        for (int i = 0; i < 64; ++i){ dbase[i] = a; a += dh[i]; dh[i] = 0; }
    }
    __syncthreads();
    int pos = dbase[bin] + atomicAdd(&dh[bin], 1);
    perm[b*512 + pos] = gnode;
    for (int t = tid; t < cnt; t += 512){
        uint ed = sedge[t];
        int p = atomicAdd(&cur[ed >> 19], 1);
        csr[p] = (int)(ed & 0x7FFFFu);
    }
    // prescale this bucket's 512 nodes: xs[node] = fp8(x*dinv), 64B rows (58 real)
    const size_t n0 = (size_t)b*512;
    for (int i = tid; i < 512*16; i += 512){
        int n = i >> 4, c = i & 15;
        float dvn = sdinv[n];
        float a0 = 0.f, a1 = 0.f, a2 = 0.f, a3 = 0.f;
        int cb = c*4;
        if (cb + 1 < 58){
            float2 v = *(const float2*)&x[(n0 + n)*58 + cb];
            a0 = v.x * dvn; a1 = v.y * dvn;
        }
        if (cb + 3 < 58){
            float2 v = *(const float2*)&x[(n0 + n)*58 + cb + 2];
            a2 = v.x * dvn; a3 = v.y * dvn;
        }
        xs32[(n0 + n)*16 + c] = pk4f8(a0, a1, a2, a3);
    }
}

// ---- conv1 gather: 8 lanes/node x uint2 (8 fp8 = 8 cols), 8 edges batched ----

__global__ __launch_bounds__(256) void k_gather1(
    const int* __restrict__ rs, const int* __restrict__ re,
    const int* __restrict__ csr, const float* __restrict__ dinv,
    const int* __restrict__ perm,
    const uint2* __restrict__ feat2,   // xs [N] rows of 64B fp8
    u16* __restrict__ out)             // agg1 [N][64] bf16
{
    int slot = (blockIdx.x*256 + threadIdx.x) >> 3;
    int c4 = threadIdx.x & 7;
    int node = perm[slot];
    uint2 u = feat2[((uint)node << 3) + c4];
    f32x2 s0 = f8lo(u.x), s1 = f8hi(u.x), s2 = f8lo(u.y), s3 = f8hi(u.y);
    float a0 = s0.x, a1 = s0.y, a2 = s1.x, a3 = s1.y;
    float a4 = s2.x, a5 = s2.y, a6 = s3.x, a7 = s3.y;
    int e = rs[node];
    const int e1 = re[node];
    while (e < e1){
        const int last = e1 - 1;
        int idx[8];
        #pragma unroll
        for (int k = 0; k < 8; ++k) idx[k] = csr[min(e + k, last)];
        uint2 uu[8];
        #pragma unroll
        for (int k = 0; k < 8; ++k) uu[k] = feat2[((uint)idx[k] << 3) + c4];
        #pragma unroll
        for (int k = 0; k < 8; ++k){
            if (e + k < e1){
                f32x2 p0 = f8lo(uu[k].x), p1 = f8hi(uu[k].x);
                f32x2 p2 = f8lo(uu[k].y), p3 = f8hi(uu[k].y);
                a0 += p0.x; a1 += p0.y; a2 += p1.x; a3 += p1.y;
                a4 += p2.x; a5 += p2.y; a6 += p3.x; a7 += p3.y;
            }
        }
        e += 8;
    }
    float di = dinv[node];
    a0 *= di; a1 *= di; a2 *= di; a3 *= di;
    a4 *= di; a5 *= di; a6 *= di; a7 *= di;
    uint4 w;
    w.x = pk(a0,a1); w.y = pk(a2,a3); w.z = pk(a4,a5); w.w = pk(a6,a7);
    *(uint4*)&out[(size_t)node*64 + c4*8] = w;
}

// ---- conv MLP: ts = fp8((relu(agg1 @ W1 + b1) @ W2) * dinv)  (MFMA, 128 rows/block) ----

__global__ __launch_bounds__(512) void k_conv_mlp(
    const u16* __restrict__ A,      // agg1 [N][64] (58 real cols, rest 0)
    const u16* __restrict__ w1t,    // [96][64] bf16 (transposed, k-padded)
    const float* __restrict__ b1,   // [96]
    const u16* __restrict__ w2t,    // [48][96] bf16 (transposed)
    const float* __restrict__ dinv,
    uint* __restrict__ ts32)        // [N] rows of 64B fp8 (48 real, rest 0)
{
    __shared__ __align__(16) u16 As[128][72];
    __shared__ __align__(16) u16 Bt1[96][72];
    __shared__ __align__(16) u16 Bt2[48][104];
    __shared__ __align__(16) u16 sh1[128][104];
    __shared__ float sb1[96];
    const int tid = threadIdx.x;
    {
        const u16* Ab = A + (size_t)blockIdx.x*128*64;
        for (int i = tid; i < 1024; i += 512){
            int r = i >> 3, s = i & 7;
            *(uint4*)&As[r][s*8] = *(const uint4*)&Ab[r*64 + s*8];
        }
    }
    for (int i = tid; i < 768; i += 512){
        int n = i >> 3, s = i & 7;
        *(uint4*)&Bt1[n][s*8] = *(const uint4*)&w1t[n*64 + s*8];
    }
    for (int i = tid; i < 576; i += 512){
        int n = i / 12, s = i % 12;
        *(uint4*)&Bt2[n][s*8] = *(const uint4*)&w2t[n*96 + s*8];
    }
    if (tid < 96) sb1[tid] = b1[tid];
    __syncthreads();

    const int wv = tid >> 6, l = tid & 63;
    const int lr = l & 15, lg = l >> 4;
    const int r0 = wv*16;              // 8 waves x 16 rows = 128 rows

    f32x4 acc1[6] = {};
    #pragma unroll
    for (int s = 0; s < 2; ++s){
        s16x8 af = *(const s16x8*)&As[r0+lr][s*32 + lg*8];
        #pragma unroll
        for (int t = 0; t < 6; ++t){
            s16x8 bf = *(const s16x8*)&Bt1[t*16+lr][s*32 + lg*8];
            acc1[t] = __builtin_amdgcn_mfma_f32_16x16x32_bf16(af, bf, acc1[t], 0, 0, 0);
        }
    }
    #pragma unroll
    for (int t = 0; t < 6; ++t){
        int col = t*16 + lr;
        float bias = sb1[col];
        #pragma unroll
        for (int r = 0; r < 4; ++r)
            sh1[r0 + lg*4 + r][col] = f2b(fmaxf(acc1[t][r] + bias, 0.f));
    }
    __syncthreads();

    f32x4 acc2[3] = {};
    #pragma unroll
    for (int s = 0; s < 3; ++s){
        s16x8 af = *(const s16x8*)&sh1[r0+lr][s*32 + lg*8];
        #pragma unroll
        for (int t = 0; t < 3; ++t){
            s16x8 bf = *(const s16x8*)&Bt2[t*16+lr][s*32 + lg*8];
            acc2[t] = __builtin_amdgcn_mfma_f32_16x16x32_bf16(af, bf, acc2[t], 0, 0, 0);
        }
    }
    size_t gbase = (size_t)blockIdx.x*128;
    // stage outputs (bf16) into sh1 cols 0..47 of this wave's own rows
    #pragma unroll
    for (int r = 0; r < 4; ++r){
        int row = r0 + lg*4 + r;
        float dv = dinv[gbase + row];
        #pragma unroll
        for (int t = 0; t < 3; ++t)
            sh1[row][t*16 + lr] = f2b(acc2[t][r] * dv);
    }
    __syncthreads();
    // repack wave's 16 rows x 16 uints (4 fp8 each), pad cols 48..63 = 0
    #pragma unroll
    for (int it = 0; it < 4; ++it){
        int item = it*64 + l;
        int row = r0 + (item >> 4);
        int c = item & 15;
        uint w = 0;
        if (c < 12){
            float b0 = bl((uint)sh1[row][c*4+0]);
            float b1_ = bl((uint)sh1[row][c*4+1]);
            float b2_ = bl((uint)sh1[row][c*4+2]);
            float b3_ = bl((uint)sh1[row][c*4+3]);
            w = pk4f8(b0, b1_, b2_, b3_);
        }
        ts32[(gbase + row)*16 + c] = w;
    }
}

// ---- conv2 gather: 8 lanes/node x uint2 fp8 (48 real cols), dense-48 masked write ----

__global__ __launch_bounds__(256) void k_gather2(
    const int* __restrict__ rs, const int* __restrict__ re,
    const int* __restrict__ csr, const float* __restrict__ dinv,
    const int* __restrict__ perm,
    const uint2* __restrict__ feat2,   // ts [N] rows of 64B fp8 (48 real)
    const float* __restrict__ bias,
    u16* __restrict__ out)             // agg2 dense [N][48] bf16
{
    int slot = (blockIdx.x*256 + threadIdx.x) >> 3;
    int c4 = threadIdx.x & 7;
    int node = perm[slot];
    uint2 u = feat2[((uint)node << 3) + c4];
    f32x2 s0 = f8lo(u.x), s1 = f8hi(u.x), s2 = f8lo(u.y), s3 = f8hi(u.y);
    float a0 = s0.x, a1 = s0.y, a2 = s1.x, a3 = s1.y;
    float a4 = s2.x, a5 = s2.y, a6 = s3.x, a7 = s3.y;
    int e = rs[node];
    const int e1 = re[node];
    while (e < e1){
        const int last = e1 - 1;
        int idx[8];
        #pragma unroll
        for (int k = 0; k < 8; ++k) idx[k] = csr[min(e + k, last)];
        uint2 uu[8];
        #pragma unroll
        for (int k = 0; k < 8; ++k) uu[k] = feat2[((uint)idx[k] << 3) + c4];
        #pragma unroll
        for (int k = 0; k < 8; ++k){
            if (e + k < e1){
                f32x2 p0 = f8lo(uu[k].x), p1 = f8hi(uu[k].x);
                f32x2 p2 = f8lo(uu[k].y), p3 = f8hi(uu[k].y);
                a0 += p0.x; a1 += p0.y; a2 += p1.x; a3 += p1.y;
                a4 += p2.x; a5 += p2.y; a6 += p3.x; a7 += p3.y;
            }
        }
        e += 8;
    }
    float di = dinv[node];
    if (c4 < 6){
        float4 bz0 = *(const float4*)&bias[8*c4];
        float4 bz1 = *(const float4*)&bias[8*c4 + 4];
        a0 = fmaxf(a0*di + bz0.x, 0.f); a1 = fmaxf(a1*di + bz0.y, 0.f);
        a2 = fmaxf(a2*di + bz0.z, 0.f); a3 = fmaxf(a3*di + bz0.w, 0.f);
        a4 = fmaxf(a4*di + bz1.x, 0.f); a5 = fmaxf(a5*di + bz1.y, 0.f);
        a6 = fmaxf(a6*di + bz1.z, 0.f); a7 = fmaxf(a7*di + bz1.w, 0.f);
        uint4 w;
        w.x = pk(a0,a1); w.y = pk(a2,a3); w.z = pk(a4,a5); w.w = pk(a6,a7);
        *(uint4*)&out[(size_t)node*48 + c4*8] = w;
    }
}

// ---- fused MLP head: 32 graphs/block, 512 threads (8 waves), g1 in LDS, l2/l3 fused ----

__global__ __launch_bounds__(512) void k_head(
    const u16* __restrict__ A,      // agg2, graph rows [8192][1920] bf16
    const u16* __restrict__ l1wt,   // [256][1920]
    const float* __restrict__ l1b,
    const u16* __restrict__ l2wt,   // [64][256]
    const float* __restrict__ l2b,
    const float* __restrict__ l3w, const float* __restrict__ l3b,
    float* __restrict__ out)
{
    __shared__ __align__(16) u16 As[32][72];
    __shared__ __align__(16) u16 Bt[256][72];
    __shared__ float part[32][4];
    u16 (*sh1)[264] = (u16(*)[264])&Bt[0][0];
    const int tid = threadIdx.x;
    const int g0 = blockIdx.x*32;
    const int w = tid >> 6, l = tid & 63;
    const int lr = l & 15, lg = l >> 4;
    const int r0 = (w & 1)*16;         // 2 row-halves
    const int c0 = (w >> 1)*64;        // 4 col-quarters of 256
    f32x4 acc[4] = {};
    for (int k0 = 0; k0 < 1920; k0 += 64){
        __syncthreads();
        if (tid < 256){
            int r = tid >> 3, s = tid & 7;
            *(uint4*)&As[r][s*8] = *(const uint4*)&A[(size_t)(g0+r)*1920 + k0 + s*8];
        }
        for (int i = tid; i < 2048; i += 512){
            int n = i >> 3, s = i & 7;
            *(uint4*)&Bt[n][s*8] = *(const uint4*)&l1wt[(size_t)n*1920 + k0 + s*8];
        }
        __syncthreads();
        #pragma unroll
        for (int s = 0; s < 2; ++s){
            s16x8 af = *(const s16x8*)&As[r0+lr][s*32 + lg*8];
            #pragma unroll
            for (int t = 0; t < 4; ++t){
                s16x8 bf = *(const s16x8*)&Bt[c0 + t*16 + lr][s*32 + lg*8];
                acc[t] = __builtin_amdgcn_mfma_f32_16x16x32_bf16(af, bf, acc[t], 0, 0, 0);
            }
        }
    }
    __syncthreads();   // everyone done reading Bt before overlay write
    #pragma unroll
    for (int t = 0; t < 4; ++t){
        int col = c0 + t*16 + lr;
        float bs = l1b[col];
        #pragma unroll
        for (int r = 0; r < 4; ++r)
            sh1[r0 + lg*4 + r][col] = f2b(fmaxf(acc[t][r] + bs, 0.f));
    }
    __syncthreads();
    // l2: each wave computes 16 output cols for its 16 rows
    f32x4 acc2 = {};
    const int col = (w >> 1)*16 + lr;
    #pragma unroll
    for (int s = 0; s < 8; ++s){
        s16x8 af = *(const s16x8*)&sh1[r0+lr][s*32 + lg*8];
        s16x8 bf = *(const s16x8*)&l2wt[(size_t)col*256 + s*32 + lg*8];
        acc2 = __builtin_amdgcn_mfma_f32_16x16x32_bf16(af, bf, acc2, 0, 0, 0);
    }
    float lb = l2b[col], lw = l3w[col];
    float p[4];
    #pragma unroll
    for (int r = 0; r < 4; ++r)
        p[r] = fmaxf(acc2[r] + lb, 0.f) * lw;
    #pragma unroll
    for (int o = 1; o < 16; o <<= 1){
        #pragma unroll
        for (int r = 0; r < 4; ++r) p[r] += __shfl_xor(p[r], o);
    }
    if (lr == 0){
        #pragma unroll
        for (int r = 0; r < 4; ++r)
            part[r0 + lg*4 + r][w>>1] = p[r];
    }
    __syncthreads();
    if (tid < 32)
        out[g0 + tid] = 1.0f / (1.0f + expf(-(part[tid][0] + part[tid][1]
                                            + part[tid][2] + part[tid][3] + l3b[0])));
}

extern "C" void kernel_launch(void* const* d_in, const int* in_sizes, int n_in,
                              void* d_out, int out_size, void* d_ws, size_t ws_size,
                              hipStream_t stream){
    const float* x   = (const float*)d_in[0];
    const int*   ei  = (const int*)  d_in[1];
    const int*   src = ei;
    const int*   dst = ei + N_EDGES;
    const float* W1  = (const float*)d_in[2];
    const float* b1  = (const float*)d_in[3];
    const float* W2  = (const float*)d_in[4];
    const float* b2  = (const float*)d_in[5];
    const float* l1w = (const float*)d_in[6];
    const float* l1b = (const float*)d_in[7];
    const float* l2w = (const float*)d_in[8];
    const float* l2b = (const float*)d_in[9];
    const float* l3w = (const float*)d_in[10];
    const float* l3b = (const float*)d_in[11];
    float* out = (float*)d_out;

    char* w = (char*)d_ws;
    auto alloc = [&](size_t bytes){ void* p = (void*)w; w += (bytes + 255) & ~(size_t)255; return p; };
    float* dinv    = (float*)alloc((size_t)N_NODES*4);
    int*   rowst   = (int*)  alloc((size_t)N_NODES*4);
    int*   rend    = (int*)  alloc((size_t)N_NODES*4);
    int*   perm    = (int*)  alloc((size_t)N_NODES*4);
    int*   gcur    = (int*)  alloc(NB*4);
    u16*   w1t     = (u16*)  alloc(96*64*2);
    u16*   w2t     = (u16*)  alloc(48*96*2);
    u16*   l1wt    = (u16*)  alloc((size_t)256*1920*2);
    u16*   l2wt    = (u16*)  alloc((size_t)64*256*2);
    int*   csr     = (int*)  alloc((size_t)NB*BCAPE*4);
    uint*  staging = (uint*) alloc((size_t)NB*BCAPE*4);
    char*  BUF_P   = (char*) alloc((size_t)N_NODES*64);     // xs32 -> ts32 (fp8, 21MB)
    char*  BUF_Q   = (char*) alloc((size_t)N_NODES*64*2);   // agg1 -> agg2

    uint* xs32 = (uint*)BUF_P;          // [bucket .. gather1], fp8 [N][64B]
    uint* ts32 = (uint*)BUF_P;          // [conv_mlp .. gather2], fp8 [N][64B]
    u16*  agg1 = (u16*) BUF_Q;          // [gather1 .. conv_mlp], bf16 [N][64]
    u16*  agg2 = (u16*) BUF_Q;          // [gather2 .. head], bf16 dense [N][48]

    // prep: weight transposes + gcur zero (one launch)
    k_prep     <<<129, 256, 0, stream>>>(W1, W2, l1w, l2w, w1t, w2t, l1wt, l2wt, gcur);

    // bucketed CSR build (fixed-cap buckets) + fused fp8 x prescale
    k_partition<<<640, 256, 0, stream>>>(src, dst, gcur, staging);
    k_bucket   <<<640, 512, 0, stream>>>(staging, gcur, x, rowst, rend, dinv, csr, perm, xs32);

    // conv1: fp8 gather -> MFMA conv -> fp8 ts
    k_gather1  <<<10240, 256, 0, stream>>>(rowst, rend, csr, dinv, perm,
                                           (const uint2*)xs32, agg1);
    k_conv_mlp <<<2560,  512, 0, stream>>>(agg1, w1t, b1, w2t, dinv, ts32);

    // conv2: fp8 gather + bias + relu -> dense-48 agg2
    k_gather2  <<<10240, 256, 0, stream>>>(rowst, rend, csr, dinv, perm,
                                           (const uint2*)ts32, b2, agg2);

    // fused MLP head
    k_head     <<<256, 512, 0, stream>>>(agg2, l1wt, l1b, l2wt, l2b, l3w, l3b, out);
}

// Round 13
// 315.837 us; speedup vs baseline: 1.1444x; 1.0164x over previous
//
#include <hip/hip_runtime.h>

#define N_NODES 327680
#define N_EDGES 2621440
#define NGRAPH  8192
#define NB      640          // dst buckets (512 nodes each)
#define BCAPE   4608         // fixed per-bucket capacity (mean 4096, +8 sigma)

typedef unsigned int uint;
typedef unsigned short u16;
typedef __attribute__((ext_vector_type(8))) short s16x8;
typedef __attribute__((ext_vector_type(4))) float f32x4;
typedef __attribute__((ext_vector_type(2))) float f32x2;

__device__ __forceinline__ float bl(uint u){ return __uint_as_float(u << 16); }
__device__ __forceinline__ float bh(uint u){ return __uint_as_float(u & 0xffff0000u); }
__device__ __forceinline__ u16 f2b(float f){
    uint u = __float_as_uint(f);
    u += 0x7fffu + ((u>>16)&1u);          // round-to-nearest-even
    return (u16)(u>>16);
}
__device__ __forceinline__ uint pk(float a, float b){
    return (uint)f2b(a) | ((uint)f2b(b) << 16);
}
// fp8 e4m3 HW converts (gfx950)
__device__ __forceinline__ f32x2 f8lo(uint w){ return __builtin_amdgcn_cvt_pk_f32_fp8((int)w, false); }
__device__ __forceinline__ f32x2 f8hi(uint w){ return __builtin_amdgcn_cvt_pk_f32_fp8((int)w, true); }
__device__ __forceinline__ uint pk4f8(float a, float b, float c, float d){
    int w = __builtin_amdgcn_cvt_pk_fp8_f32(a, b, 0, false);
    w = __builtin_amdgcn_cvt_pk_fp8_f32(c, d, w, true);
    return (uint)w;
}

// ---------------- prep: weight transposes (bf16) + gcur zero, one launch ----------------

__device__ void tr_tile(const float* __restrict__ in, u16* __restrict__ out,
                        int K, int N, int Kpad, int kb, int nb){
    __shared__ u16 t[64][72];
    for (int i = threadIdx.x; i < 4096; i += 256){
        int k = i >> 6, n = i & 63;
        int gk = kb + k, gn = nb + n;
        float v = (gk < K && gn < N) ? in[(size_t)gk*N + gn] : 0.f;
        t[n][k] = f2b(v);
    }
    __syncthreads();
    for (int i = threadIdx.x; i < 4096; i += 256){
        int n = i >> 6, k = i & 63;
        int gk = kb + k, gn = nb + n;
        if (gn < N && gk < Kpad) out[(size_t)gn*Kpad + gk] = t[n][k];
    }
}

__global__ __launch_bounds__(256) void k_prep(
    const float* __restrict__ W1, const float* __restrict__ W2,
    const float* __restrict__ l1w, const float* __restrict__ l2w,
    u16* __restrict__ w1t, u16* __restrict__ w2t,
    u16* __restrict__ l1wt, u16* __restrict__ l2wt, int* __restrict__ gcur)
{
    int b = blockIdx.x;
    if (b < 120)      tr_tile(l1w, l1wt, 1920, 256, 1920, (b%30)*64, (b/30)*64);
    else if (b < 124) tr_tile(l2w, l2wt, 256,  64,  256,  (b-120)*64, 0);
    else if (b < 126) tr_tile(W1,  w1t,  58,   96,  64,   0, (b-124)*64);
    else if (b < 128) tr_tile(W2,  w2t,  96,   48,  96,   (b-126)*64, 0);
    else {
        for (int i = threadIdx.x; i < NB; i += 256) gcur[i] = 0;
    }
}

// ------- partition edges into fixed-cap dst-buckets (packed uint, single-pass ranks) -------

__global__ __launch_bounds__(256) void k_partition(
    const int* __restrict__ src, const int* __restrict__ dst,
    int* __restrict__ gcur, uint* __restrict__ staging)
{
    __shared__ int cnt[NB], base_[NB];
    int tid = threadIdx.x;
    for (int i = tid; i < NB; i += 256) cnt[i] = 0;
    __syncthreads();
    int e0 = blockIdx.x*4096;
    int d[16], r[16];
    #pragma unroll
    for (int j = 0; j < 16; ++j){
        d[j] = dst[e0 + j*256 + tid];
        r[j] = atomicAdd(&cnt[d[j] >> 9], 1);   // rank within (block,bucket)
    }
    __syncthreads();
    for (int i = tid; i < NB; i += 256)
        base_[i] = atomicAdd(&gcur[i], cnt[i]);
    __syncthreads();
    #pragma unroll
    for (int j = 0; j < 16; ++j){
        int e = e0 + j*256 + tid;
        int b = d[j] >> 9;
        staging[(uint)b*BCAPE + base_[b] + r[j]] = (uint)src[e] | ((uint)(d[j] & 511) << 19);
    }
}

// ---- per-bucket: degree, dinv, row starts, csr place, degree-sorted perm, x prescale(fp8) ----

__global__ __launch_bounds__(512) void k_bucket(
    const uint* __restrict__ staging, const int* __restrict__ gcur,
    const float* __restrict__ x,
    int* __restrict__ rowst, int* __restrict__ rendg, float* __restrict__ dinvg,
    int* __restrict__ csr, int* __restrict__ perm, uint* __restrict__ xs32)
{
    __shared__ uint sedge[BCAPE];
    __shared__ int deg[512];
    __shared__ int cur[512];
    __shared__ int wsum[8];
    __shared__ int dh[64], dbase[64];
    __shared__ float sdinv[512];
    const int b = blockIdx.x;
    const int tid = threadIdx.x;
    const int lo = b*BCAPE;
    int cnt = gcur[b];
    if (cnt > BCAPE) cnt = BCAPE;   // safety (8-sigma margin, never expected)
    deg[tid] = 0;
    if (tid < 64) dh[tid] = 0;
    __syncthreads();
    for (int t = tid; t < cnt; t += 512){
        uint ed = staging[lo + t];
        sedge[t] = ed;
        atomicAdd(&deg[ed >> 19], 1);
    }
    __syncthreads();
    int d = deg[tid];
    // wave-level inclusive scan (64 lanes), then cross-wave prefix
    int incl = d;
    #pragma unroll
    for (int o = 1; o < 64; o <<= 1){
        int t = __shfl_up(incl, o);
        if ((tid & 63) >= o) incl += t;
    }
    if ((tid & 63) == 63) wsum[tid >> 6] = incl;
    __syncthreads();
    if (tid == 0){
        int a = 0;
        #pragma unroll
        for (int i = 0; i < 8; ++i){ int v = wsum[i]; wsum[i] = a; a += v; }
    }
    __syncthreads();
    incl += wsum[tid >> 6];
    int excl = incl - d;
    int gnode = b*512 + tid;
    float dv = 1.0f / sqrtf((float)(d + 1));
    rowst[gnode] = lo + excl;
    rendg[gnode] = lo + incl;
    dinvg[gnode] = dv;
    sdinv[tid] = dv;
    cur[tid] = lo + excl;
    int bin = min(d, 63);
    atomicAdd(&dh[bin], 1);
    __syncthreads();
    if (tid == 0){
        int a = 0;
        #pragma unroll
        for (int i = 0; i < 64; ++i){ dbase[i] = a; a += dh[i]; dh[i] = 0; }
    }
    __syncthreads();
    int pos = dbase[bin] + atomicAdd(&dh[bin], 1);
    perm[b*512 + pos] = gnode;
    for (int t = tid; t < cnt; t += 512){
        uint ed = sedge[t];
        int p = atomicAdd(&cur[ed >> 19], 1);
        csr[p] = (int)(ed & 0x7FFFFu);
    }
    // prescale this bucket's 512 nodes: xs[node] = fp8(x*dinv), 64B rows (58 real)
    const size_t n0 = (size_t)b*512;
    for (int i = tid; i < 512*16; i += 512){
        int n = i >> 4, c = i & 15;
        float dvn = sdinv[n];
        float a0 = 0.f, a1 = 0.f, a2 = 0.f, a3 = 0.f;
        int cb = c*4;
        if (cb + 1 < 58){
            float2 v = *(const float2*)&x[(n0 + n)*58 + cb];
            a0 = v.x * dvn; a1 = v.y * dvn;
        }
        if (cb + 3 < 58){
            float2 v = *(const float2*)&x[(n0 + n)*58 + cb + 2];
            a2 = v.x * dvn; a3 = v.y * dvn;
        }
        xs32[(n0 + n)*16 + c] = pk4f8(a0, a1, a2, a3);
    }
}

// ---- conv1 gather: 8 lanes/node x uint2 (8 fp8 cols), 8 edges batched, fp8 out ----

__global__ __launch_bounds__(256) void k_gather1(
    const int* __restrict__ rs, const int* __restrict__ re,
    const int* __restrict__ csr, const float* __restrict__ dinv,
    const int* __restrict__ perm,
    const uint2* __restrict__ feat2,   // xs [N] rows of 64B fp8
    uint* __restrict__ out)            // agg1 fp8 [N][64B]
{
    int slot = (blockIdx.x*256 + threadIdx.x) >> 3;
    int c4 = threadIdx.x & 7;
    int node = perm[slot];
    uint2 u = feat2[((uint)node << 3) + c4];
    f32x2 s0 = f8lo(u.x), s1 = f8hi(u.x), s2 = f8lo(u.y), s3 = f8hi(u.y);
    float a0 = s0.x, a1 = s0.y, a2 = s1.x, a3 = s1.y;
    float a4 = s2.x, a5 = s2.y, a6 = s3.x, a7 = s3.y;
    int e = rs[node];
    const int e1 = re[node];
    while (e < e1){
        const int last = e1 - 1;
        int idx[8];
        #pragma unroll
        for (int k = 0; k < 8; ++k) idx[k] = csr[min(e + k, last)];
        uint2 uu[8];
        #pragma unroll
        for (int k = 0; k < 8; ++k) uu[k] = feat2[((uint)idx[k] << 3) + c4];
        #pragma unroll
        for (int k = 0; k < 8; ++k){
            if (e + k < e1){
                f32x2 p0 = f8lo(uu[k].x), p1 = f8hi(uu[k].x);
                f32x2 p2 = f8lo(uu[k].y), p3 = f8hi(uu[k].y);
                a0 += p0.x; a1 += p0.y; a2 += p1.x; a3 += p1.y;
                a4 += p2.x; a5 += p2.y; a6 += p3.x; a7 += p3.y;
            }
        }
        e += 8;
    }
    float di = dinv[node];
    a0 *= di; a1 *= di; a2 *= di; a3 *= di;
    a4 *= di; a5 *= di; a6 *= di; a7 *= di;
    uint2 w;
    w.x = pk4f8(a0, a1, a2, a3);
    w.y = pk4f8(a4, a5, a6, a7);
    *(uint2*)&out[((size_t)node << 4) + c4*2] = w;
}

// ---- conv MLP: ts = fp8((relu(agg1 @ W1 + b1) @ W2) * dinv)  (MFMA, 128 rows/block) ----

__global__ __launch_bounds__(512) void k_conv_mlp(
    const uint* __restrict__ A8,    // agg1 fp8 [N][16 uints] (58 real cols, rest 0)
    const u16* __restrict__ w1t,    // [96][64] bf16 (transposed, k-padded)
    const float* __restrict__ b1,   // [96]
    const u16* __restrict__ w2t,    // [48][96] bf16 (transposed)
    const float* __restrict__ dinv,
    uint* __restrict__ ts32)        // [N] rows of 64B fp8 (48 real, rest 0)
{
    __shared__ __align__(16) u16 As[128][72];
    __shared__ __align__(16) u16 Bt1[96][72];
    __shared__ __align__(16) u16 Bt2[48][104];
    __shared__ __align__(16) u16 sh1[128][104];
    __shared__ float sb1[96];
    const int tid = threadIdx.x;
    {
        const uint* Ab = A8 + (size_t)blockIdx.x*128*16;
        for (int i = tid; i < 2048; i += 512){
            int r = i >> 4, c = i & 15;
            uint v = Ab[r*16 + c];
            f32x2 lo = f8lo(v), hi = f8hi(v);
            uint2 st;
            st.x = pk(lo.x, lo.y);
            st.y = pk(hi.x, hi.y);
            *(uint2*)&As[r][c*4] = st;
        }
    }
    for (int i = tid; i < 768; i += 512){
        int n = i >> 3, s = i & 7;
        *(uint4*)&Bt1[n][s*8] = *(const uint4*)&w1t[n*64 + s*8];
    }
    for (int i = tid; i < 576; i += 512){
        int n = i / 12, s = i % 12;
        *(uint4*)&Bt2[n][s*8] = *(const uint4*)&w2t[n*96 + s*8];
    }
    if (tid < 96) sb1[tid] = b1[tid];
    __syncthreads();

    const int wv = tid >> 6, l = tid & 63;
    const int lr = l & 15, lg = l >> 4;
    const int r0 = wv*16;              // 8 waves x 16 rows = 128 rows

    f32x4 acc1[6] = {};
    #pragma unroll
    for (int s = 0; s < 2; ++s){
        s16x8 af = *(const s16x8*)&As[r0+lr][s*32 + lg*8];
        #pragma unroll
        for (int t = 0; t < 6; ++t){
            s16x8 bf = *(const s16x8*)&Bt1[t*16+lr][s*32 + lg*8];
            acc1[t] = __builtin_amdgcn_mfma_f32_16x16x32_bf16(af, bf, acc1[t], 0, 0, 0);
        }
    }
    #pragma unroll
    for (int t = 0; t < 6; ++t){
        int col = t*16 + lr;
        float bias = sb1[col];
        #pragma unroll
        for (int r = 0; r < 4; ++r)
            sh1[r0 + lg*4 + r][col] = f2b(fmaxf(acc1[t][r] + bias, 0.f));
    }
    __syncthreads();

    f32x4 acc2[3] = {};
    #pragma unroll
    for (int s = 0; s < 3; ++s){
        s16x8 af = *(const s16x8*)&sh1[r0+lr][s*32 + lg*8];
        #pragma unroll
        for (int t = 0; t < 3; ++t){
            s16x8 bf = *(const s16x8*)&Bt2[t*16+lr][s*32 + lg*8];
            acc2[t] = __builtin_amdgcn_mfma_f32_16x16x32_bf16(af, bf, acc2[t], 0, 0, 0);
        }
    }
    size_t gbase = (size_t)blockIdx.x*128;
    // stage outputs (bf16) into sh1 cols 0..47 of this wave's own rows
    #pragma unroll
    for (int r = 0; r < 4; ++r){
        int row = r0 + lg*4 + r;
        float dv = dinv[gbase + row];
        #pragma unroll
        for (int t = 0; t < 3; ++t)
            sh1[row][t*16 + lr] = f2b(acc2[t][r] * dv);
    }
    __syncthreads();
    // repack wave's 16 rows x 16 uints (4 fp8 each), pad cols 48..63 = 0
    #pragma unroll
    for (int it = 0; it < 4; ++it){
        int item = it*64 + l;
        int row = r0 + (item >> 4);
        int c = item & 15;
        uint w = 0;
        if (c < 12){
            float b0 = bl((uint)sh1[row][c*4+0]);
            float b1_ = bl((uint)sh1[row][c*4+1]);
            float b2_ = bl((uint)sh1[row][c*4+2]);
            float b3_ = bl((uint)sh1[row][c*4+3]);
            w = pk4f8(b0, b1_, b2_, b3_);
        }
        ts32[(gbase + row)*16 + c] = w;
    }
}

// ---- conv2 gather: 8 lanes/node x uint2 fp8 (48 real cols), dense-48 masked write ----

__global__ __launch_bounds__(256) void k_gather2(
    const int* __restrict__ rs, const int* __restrict__ re,
    const int* __restrict__ csr, const float* __restrict__ dinv,
    const int* __restrict__ perm,
    const uint2* __restrict__ feat2,   // ts [N] rows of 64B fp8 (48 real)
    const float* __restrict__ bias,
    u16* __restrict__ out)             // agg2 dense [N][48] bf16
{
    int slot = (blockIdx.x*256 + threadIdx.x) >> 3;
    int c4 = threadIdx.x & 7;
    int node = perm[slot];
    uint2 u = feat2[((uint)node << 3) + c4];
    f32x2 s0 = f8lo(u.x), s1 = f8hi(u.x), s2 = f8lo(u.y), s3 = f8hi(u.y);
    float a0 = s0.x, a1 = s0.y, a2 = s1.x, a3 = s1.y;
    float a4 = s2.x, a5 = s2.y, a6 = s3.x, a7 = s3.y;
    int e = rs[node];
    const int e1 = re[node];
    while (e < e1){
        const int last = e1 - 1;
        int idx[8];
        #pragma unroll
        for (int k = 0; k < 8; ++k) idx[k] = csr[min(e + k, last)];
        uint2 uu[8];
        #pragma unroll
        for (int k = 0; k < 8; ++k) uu[k] = feat2[((uint)idx[k] << 3) + c4];
        #pragma unroll
        for (int k = 0; k < 8; ++k){
            if (e + k < e1){
                f32x2 p0 = f8lo(uu[k].x), p1 = f8hi(uu[k].x);
                f32x2 p2 = f8lo(uu[k].y), p3 = f8hi(uu[k].y);
                a0 += p0.x; a1 += p0.y; a2 += p1.x; a3 += p1.y;
                a4 += p2.x; a5 += p2.y; a6 += p3.x; a7 += p3.y;
            }
        }
        e += 8;
    }
    float di = dinv[node];
    if (c4 < 6){
        float4 bz0 = *(const float4*)&bias[8*c4];
        float4 bz1 = *(const float4*)&bias[8*c4 + 4];
        a0 = fmaxf(a0*di + bz0.x, 0.f); a1 = fmaxf(a1*di + bz0.y, 0.f);
        a2 = fmaxf(a2*di + bz0.z, 0.f); a3 = fmaxf(a3*di + bz0.w, 0.f);
        a4 = fmaxf(a4*di + bz1.x, 0.f); a5 = fmaxf(a5*di + bz1.y, 0.f);
        a6 = fmaxf(a6*di + bz1.z, 0.f); a7 = fmaxf(a7*di + bz1.w, 0.f);
        uint4 w;
        w.x = pk(a0,a1); w.y = pk(a2,a3); w.z = pk(a4,a5); w.w = pk(a6,a7);
        *(uint4*)&out[(size_t)node*48 + c4*8] = w;
    }
}

// ---- fused MLP head: 32 graphs/block, 512 threads (8 waves), g1 in LDS, l2/l3 fused ----

__global__ __launch_bounds__(512) void k_head(
    const u16* __restrict__ A,      // agg2, graph rows [8192][1920] bf16
    const u16* __restrict__ l1wt,   // [256][1920]
    const float* __restrict__ l1b,
    const u16* __restrict__ l2wt,   // [64][256]
    const float* __restrict__ l2b,
    const float* __restrict__ l3w, const float* __restrict__ l3b,
    float* __restrict__ out)
{
    __shared__ __align__(16) u16 As[32][72];
    __shared__ __align__(16) u16 Bt[256][72];
    __shared__ float part[32][4];
    u16 (*sh1)[264] = (u16(*)[264])&Bt[0][0];
    const int tid = threadIdx.x;
    const int g0 = blockIdx.x*32;
    const int w = tid >> 6, l = tid & 63;
    const int lr = l & 15, lg = l >> 4;
    const int r0 = (w & 1)*16;         // 2 row-halves
    const int c0 = (w >> 1)*64;        // 4 col-quarters of 256
    f32x4 acc[4] = {};
    for (int k0 = 0; k0 < 1920; k0 += 64){
        __syncthreads();
        if (tid < 256){
            int r = tid >> 3, s = tid & 7;
            *(uint4*)&As[r][s*8] = *(const uint4*)&A[(size_t)(g0+r)*1920 + k0 + s*8];
        }
        for (int i = tid; i < 2048; i += 512){
            int n = i >> 3, s = i & 7;
            *(uint4*)&Bt[n][s*8] = *(const uint4*)&l1wt[(size_t)n*1920 + k0 + s*8];
        }
        __syncthreads();
        #pragma unroll
        for (int s = 0; s < 2; ++s){
            s16x8 af = *(const s16x8*)&As[r0+lr][s*32 + lg*8];
            #pragma unroll
            for (int t = 0; t < 4; ++t){
                s16x8 bf = *(const s16x8*)&Bt[c0 + t*16 + lr][s*32 + lg*8];
                acc[t] = __builtin_amdgcn_mfma_f32_16x16x32_bf16(af, bf, acc[t], 0, 0, 0);
            }
        }
    }
    __syncthreads();   // everyone done reading Bt before overlay write
    #pragma unroll
    for (int t = 0; t < 4; ++t){
        int col = c0 + t*16 + lr;
        float bs = l1b[col];
        #pragma unroll
        for (int r = 0; r < 4; ++r)
            sh1[r0 + lg*4 + r][col] = f2b(fmaxf(acc[t][r] + bs, 0.f));
    }
    __syncthreads();
    // l2: each wave computes 16 output cols for its 16 rows
    f32x4 acc2 = {};
    const int col = (w >> 1)*16 + lr;
    #pragma unroll
    for (int s = 0; s < 8; ++s){
        s16x8 af = *(const s16x8*)&sh1[r0+lr][s*32 + lg*8];
        s16x8 bf = *(const s16x8*)&l2wt[(size_t)col*256 + s*32 + lg*8];
        acc2 = __builtin_amdgcn_mfma_f32_16x16x32_bf16(af, bf, acc2, 0, 0, 0);
    }
    float lb = l2b[col], lw = l3w[col];
    float p[4];
    #pragma unroll
    for (int r = 0; r < 4; ++r)
        p[r] = fmaxf(acc2[r] + lb, 0.f) * lw;
    #pragma unroll
    for (int o = 1; o < 16; o <<= 1){
        #pragma unroll
        for (int r = 0; r < 4; ++r) p[r] += __shfl_xor(p[r], o);
    }
    if (lr == 0){
        #pragma unroll
        for (int r = 0; r < 4; ++r)
            part[r0 + lg*4 + r][w>>1] = p[r];
    }
    __syncthreads();
    if (tid < 32)
        out[g0 + tid] = 1.0f / (1.0f + expf(-(part[tid][0] + part[tid][1]
                                            + part[tid][2] + part[tid][3] + l3b[0])));
}

extern "C" void kernel_launch(void* const* d_in, const int* in_sizes, int n_in,
                              void* d_out, int out_size, void* d_ws, size_t ws_size,
                              hipStream_t stream){
    const float* x   = (const float*)d_in[0];
    const int*   ei  = (const int*)  d_in[1];
    const int*   src = ei;
    const int*   dst = ei + N_EDGES;
    const float* W1  = (const float*)d_in[2];
    const float* b1  = (const float*)d_in[3];
    const float* W2  = (const float*)d_in[4];
    const float* b2  = (const float*)d_in[5];
    const float* l1w = (const float*)d_in[6];
    const float* l1b = (const float*)d_in[7];
    const float* l2w = (const float*)d_in[8];
    const float* l2b = (const float*)d_in[9];
    const float* l3w = (const float*)d_in[10];
    const float* l3b = (const float*)d_in[11];
    float* out = (float*)d_out;

    char* w = (char*)d_ws;
    auto alloc = [&](size_t bytes){ void* p = (void*)w; w += (bytes + 255) & ~(size_t)255; return p; };
    float* dinv    = (float*)alloc((size_t)N_NODES*4);
    int*   rowst   = (int*)  alloc((size_t)N_NODES*4);
    int*   rend    = (int*)  alloc((size_t)N_NODES*4);
    int*   perm    = (int*)  alloc((size_t)N_NODES*4);
    int*   gcur    = (int*)  alloc(NB*4);
    u16*   w1t     = (u16*)  alloc(96*64*2);
    u16*   w2t     = (u16*)  alloc(48*96*2);
    u16*   l1wt    = (u16*)  alloc((size_t)256*1920*2);
    u16*   l2wt    = (u16*)  alloc((size_t)64*256*2);
    int*   csr     = (int*)  alloc((size_t)NB*BCAPE*4);
    uint*  staging = (uint*) alloc((size_t)NB*BCAPE*4);
    char*  BUF_P   = (char*) alloc((size_t)N_NODES*64);     // xs32 -> ts32 (fp8, 21MB)
    char*  BUF_Q   = (char*) alloc((size_t)N_NODES*64*2);   // agg1(fp8) -> agg2(bf16)

    uint* xs32 = (uint*)BUF_P;          // [bucket .. gather1], fp8 [N][64B]
    uint* ts32 = (uint*)BUF_P;          // [conv_mlp .. gather2], fp8 [N][64B]
    uint* agg1 = (uint*)BUF_Q;          // [gather1 .. conv_mlp], fp8 [N][64B]
    u16*  agg2 = (u16*) BUF_Q;          // [gather2 .. head], bf16 dense [N][48]

    // prep: weight transposes + gcur zero (one launch)
    k_prep     <<<129, 256, 0, stream>>>(W1, W2, l1w, l2w, w1t, w2t, l1wt, l2wt, gcur);

    // bucketed CSR build (fixed-cap buckets) + fused fp8 x prescale
    k_partition<<<640, 256, 0, stream>>>(src, dst, gcur, staging);
    k_bucket   <<<640, 512, 0, stream>>>(staging, gcur, x, rowst, rend, dinv, csr, perm, xs32);

    // conv1: fp8 gather -> MFMA conv -> fp8 ts
    k_gather1  <<<10240, 256, 0, stream>>>(rowst, rend, csr, dinv, perm,
                                           (const uint2*)xs32, agg1);
    k_conv_mlp <<<2560,  512, 0, stream>>>(agg1, w1t, b1, w2t, dinv, ts32);

    // conv2: fp8 gather + bias + relu -> dense-48 agg2
    k_gather2  <<<10240, 256, 0, stream>>>(rowst, rend, csr, dinv, perm,
                                           (const uint2*)ts32, b2, agg2);

    // fused MLP head
    k_head     <<<256, 512, 0, stream>>>(agg2, l1wt, l1b, l2wt, l2b, l3w, l3b, out);
}

// Round 14
// 310.605 us; speedup vs baseline: 1.1637x; 1.0168x over previous
//
#include <hip/hip_runtime.h>

#define N_NODES 327680
#define N_EDGES 2621440
#define NGRAPH  8192
#define NB      640          // dst buckets (512 nodes each)
#define BCAPE   4608         // fixed per-bucket capacity (mean 4096, +8 sigma)

typedef unsigned int uint;
typedef unsigned short u16;
typedef __attribute__((ext_vector_type(8))) short s16x8;
typedef __attribute__((ext_vector_type(4))) float f32x4;
typedef __attribute__((ext_vector_type(2))) float f32x2;

__device__ __forceinline__ float bl(uint u){ return __uint_as_float(u << 16); }
__device__ __forceinline__ float bh(uint u){ return __uint_as_float(u & 0xffff0000u); }
__device__ __forceinline__ u16 f2b(float f){
    uint u = __float_as_uint(f);
    u += 0x7fffu + ((u>>16)&1u);          // round-to-nearest-even
    return (u16)(u>>16);
}
__device__ __forceinline__ uint pk(float a, float b){
    return (uint)f2b(a) | ((uint)f2b(b) << 16);
}
// fp8 e4m3 HW converts (gfx950)
__device__ __forceinline__ f32x2 f8lo(uint w){ return __builtin_amdgcn_cvt_pk_f32_fp8((int)w, false); }
__device__ __forceinline__ f32x2 f8hi(uint w){ return __builtin_amdgcn_cvt_pk_f32_fp8((int)w, true); }
__device__ __forceinline__ uint pk4f8(float a, float b, float c, float d){
    int w = __builtin_amdgcn_cvt_pk_fp8_f32(a, b, 0, false);
    w = __builtin_amdgcn_cvt_pk_fp8_f32(c, d, w, true);
    return (uint)w;
}

// ---------------- prep: weight transposes (bf16) + gcur zero, one launch ----------------

__device__ void tr_tile(const float* __restrict__ in, u16* __restrict__ out,
                        int K, int N, int Kpad, int kb, int nb){
    __shared__ u16 t[64][72];
    for (int i = threadIdx.x; i < 4096; i += 256){
        int k = i >> 6, n = i & 63;
        int gk = kb + k, gn = nb + n;
        float v = (gk < K && gn < N) ? in[(size_t)gk*N + gn] : 0.f;
        t[n][k] = f2b(v);
    }
    __syncthreads();
    for (int i = threadIdx.x; i < 4096; i += 256){
        int n = i >> 6, k = i & 63;
        int gk = kb + k, gn = nb + n;
        if (gn < N && gk < Kpad) out[(size_t)gn*Kpad + gk] = t[n][k];
    }
}

__global__ __launch_bounds__(256) void k_prep(
    const float* __restrict__ W1, const float* __restrict__ W2,
    const float* __restrict__ l1w, const float* __restrict__ l2w,
    u16* __restrict__ w1t, u16* __restrict__ w2t,
    u16* __restrict__ l1wt, u16* __restrict__ l2wt, int* __restrict__ gcur)
{
    int b = blockIdx.x;
    if (b < 120)      tr_tile(l1w, l1wt, 1920, 256, 1920, (b%30)*64, (b/30)*64);
    else if (b < 124) tr_tile(l2w, l2wt, 256,  64,  256,  (b-120)*64, 0);
    else if (b < 126) tr_tile(W1,  w1t,  58,   96,  64,   0, (b-124)*64);
    else if (b < 128) tr_tile(W2,  w2t,  96,   48,  96,   (b-126)*64, 0);
    else {
        for (int i = threadIdx.x; i < NB; i += 256) gcur[i] = 0;
    }
}

// ------- partition edges into fixed-cap dst-buckets (packed uint, single-pass ranks) -------

__global__ __launch_bounds__(256) void k_partition(
    const int* __restrict__ src, const int* __restrict__ dst,
    int* __restrict__ gcur, uint* __restrict__ staging)
{
    __shared__ int cnt[NB], base_[NB];
    int tid = threadIdx.x;
    for (int i = tid; i < NB; i += 256) cnt[i] = 0;
    __syncthreads();
    int e0 = blockIdx.x*4096;
    int d[16], r[16];
    #pragma unroll
    for (int j = 0; j < 16; ++j){
        d[j] = dst[e0 + j*256 + tid];
        r[j] = atomicAdd(&cnt[d[j] >> 9], 1);   // rank within (block,bucket)
    }
    __syncthreads();
    for (int i = tid; i < NB; i += 256)
        base_[i] = atomicAdd(&gcur[i], cnt[i]);
    __syncthreads();
    #pragma unroll
    for (int j = 0; j < 16; ++j){
        int e = e0 + j*256 + tid;
        int b = d[j] >> 9;
        staging[(uint)b*BCAPE + base_[b] + r[j]] = (uint)src[e] | ((uint)(d[j] & 511) << 19);
    }
}

// ---- per-bucket: degree, dinv, row starts, csr place, degree-sorted perm, x prescale(fp8) ----

__global__ __launch_bounds__(512) void k_bucket(
    const uint* __restrict__ staging, const int* __restrict__ gcur,
    const float* __restrict__ x,
    int* __restrict__ rowst, int* __restrict__ rendg, float* __restrict__ dinvg,
    int* __restrict__ csr, int* __restrict__ perm, uint* __restrict__ xs32)
{
    __shared__ uint sedge[BCAPE];
    __shared__ int deg[512];
    __shared__ int cur[512];
    __shared__ int wsum[8];
    __shared__ int dh[64], dbase[64];
    __shared__ float sdinv[512];
    const int b = blockIdx.x;
    const int tid = threadIdx.x;
    const int lo = b*BCAPE;
    int cnt = gcur[b];
    if (cnt > BCAPE) cnt = BCAPE;   // safety (8-sigma margin, never expected)
    deg[tid] = 0;
    if (tid < 64) dh[tid] = 0;
    __syncthreads();
    for (int t = tid; t < cnt; t += 512){
        uint ed = staging[lo + t];
        sedge[t] = ed;
        atomicAdd(&deg[ed >> 19], 1);
    }
    __syncthreads();
    int d = deg[tid];
    // wave-level inclusive scan (64 lanes), then cross-wave prefix
    int incl = d;
    #pragma unroll
    for (int o = 1; o < 64; o <<= 1){
        int t = __shfl_up(incl, o);
        if ((tid & 63) >= o) incl += t;
    }
    if ((tid & 63) == 63) wsum[tid >> 6] = incl;
    __syncthreads();
    if (tid == 0){
        int a = 0;
        #pragma unroll
        for (int i = 0; i < 8; ++i){ int v = wsum[i]; wsum[i] = a; a += v; }
    }
    __syncthreads();
    incl += wsum[tid >> 6];
    int excl = incl - d;
    int gnode = b*512 + tid;
    float dv = 1.0f / sqrtf((float)(d + 1));
    rowst[gnode] = lo + excl;
    rendg[gnode] = lo + incl;
    dinvg[gnode] = dv;
    sdinv[tid] = dv;
    cur[tid] = lo + excl;
    int bin = min(d, 63);
    atomicAdd(&dh[bin], 1);
    __syncthreads();
    if (tid == 0){
        int a = 0;
        #pragma unroll
        for (int i = 0; i < 64; ++i){ dbase[i] = a; a += dh[i]; dh[i] = 0; }
    }
    __syncthreads();
    int pos = dbase[bin] + atomicAdd(&dh[bin], 1);
    perm[b*512 + pos] = gnode;
    for (int t = tid; t < cnt; t += 512){
        uint ed = sedge[t];
        int p = atomicAdd(&cur[ed >> 19], 1);
        csr[p] = (int)(ed & 0x7FFFFu);
    }
    // prescale this bucket's 512 nodes: xs[node] = fp8(x*dinv), 64B rows (58 real)
    const size_t n0 = (size_t)b*512;
    for (int i = tid; i < 512*16; i += 512){
        int n = i >> 4, c = i & 15;
        float dvn = sdinv[n];
        float a0 = 0.f, a1 = 0.f, a2 = 0.f, a3 = 0.f;
        int cb = c*4;
        if (cb + 1 < 58){
            float2 v = *(const float2*)&x[(n0 + n)*58 + cb];
            a0 = v.x * dvn; a1 = v.y * dvn;
        }
        if (cb + 3 < 58){
            float2 v = *(const float2*)&x[(n0 + n)*58 + cb + 2];
            a2 = v.x * dvn; a3 = v.y * dvn;
        }
        xs32[(n0 + n)*16 + c] = pk4f8(a0, a1, a2, a3);
    }
}

// ---- conv1 gather: 8 lanes/node x uint2 (8 fp8 cols), 8 edges batched, fp8 out ----

__global__ __launch_bounds__(256) void k_gather1(
    const int* __restrict__ rs, const int* __restrict__ re,
    const int* __restrict__ csr, const float* __restrict__ dinv,
    const int* __restrict__ perm,
    const uint2* __restrict__ feat2,   // xs [N] rows of 64B fp8
    uint* __restrict__ out)            // agg1 fp8 [N][64B]
{
    int slot = (blockIdx.x*256 + threadIdx.x) >> 3;
    int c4 = threadIdx.x & 7;
    int node = perm[slot];
    uint2 u = feat2[((uint)node << 3) + c4];
    f32x2 s0 = f8lo(u.x), s1 = f8hi(u.x), s2 = f8lo(u.y), s3 = f8hi(u.y);
    float a0 = s0.x, a1 = s0.y, a2 = s1.x, a3 = s1.y;
    float a4 = s2.x, a5 = s2.y, a6 = s3.x, a7 = s3.y;
    int e = rs[node];
    const int e1 = re[node];
    while (e < e1){
        const int last = e1 - 1;
        int idx[8];
        #pragma unroll
        for (int k = 0; k < 8; ++k) idx[k] = csr[min(e + k, last)];
        uint2 uu[8];
        #pragma unroll
        for (int k = 0; k < 8; ++k) uu[k] = feat2[((uint)idx[k] << 3) + c4];
        #pragma unroll
        for (int k = 0; k < 8; ++k){
            if (e + k < e1){
                f32x2 p0 = f8lo(uu[k].x), p1 = f8hi(uu[k].x);
                f32x2 p2 = f8lo(uu[k].y), p3 = f8hi(uu[k].y);
                a0 += p0.x; a1 += p0.y; a2 += p1.x; a3 += p1.y;
                a4 += p2.x; a5 += p2.y; a6 += p3.x; a7 += p3.y;
            }
        }
        e += 8;
    }
    float di = dinv[node];
    a0 *= di; a1 *= di; a2 *= di; a3 *= di;
    a4 *= di; a5 *= di; a6 *= di; a7 *= di;
    uint2 w;
    w.x = pk4f8(a0, a1, a2, a3);
    w.y = pk4f8(a4, a5, a6, a7);
    *(uint2*)&out[((size_t)node << 4) + c4*2] = w;
}

// ---- conv MLP: ts = fp8((relu(agg1 @ W1 + b1) @ W2) * dinv)  (MFMA, 128 rows/block) ----

__global__ __launch_bounds__(512) void k_conv_mlp(
    const uint* __restrict__ A8,    // agg1 fp8 [N][16 uints] (58 real cols, rest 0)
    const u16* __restrict__ w1t,    // [96][64] bf16 (transposed, k-padded)
    const float* __restrict__ b1,   // [96]
    const u16* __restrict__ w2t,    // [48][96] bf16 (transposed)
    const float* __restrict__ dinv,
    uint* __restrict__ ts32)        // [N] rows of 64B fp8 (48 real, rest 0)
{
    __shared__ __align__(16) u16 As[128][72];
    __shared__ __align__(16) u16 Bt1[96][72];
    __shared__ __align__(16) u16 Bt2[48][104];
    __shared__ __align__(16) u16 sh1[128][104];
    __shared__ float sb1[96];
    const int tid = threadIdx.x;
    {
        const uint* Ab = A8 + (size_t)blockIdx.x*128*16;
        for (int i = tid; i < 2048; i += 512){
            int r = i >> 4, c = i & 15;
            uint v = Ab[r*16 + c];
            f32x2 lo = f8lo(v), hi = f8hi(v);
            uint2 st;
            st.x = pk(lo.x, lo.y);
            st.y = pk(hi.x, hi.y);
            *(uint2*)&As[r][c*4] = st;
        }
    }
    for (int i = tid; i < 768; i += 512){
        int n = i >> 3, s = i & 7;
        *(uint4*)&Bt1[n][s*8] = *(const uint4*)&w1t[n*64 + s*8];
    }
    for (int i = tid; i < 576; i += 512){
        int n = i / 12, s = i % 12;
        *(uint4*)&Bt2[n][s*8] = *(const uint4*)&w2t[n*96 + s*8];
    }
    if (tid < 96) sb1[tid] = b1[tid];
    __syncthreads();

    const int wv = tid >> 6, l = tid & 63;
    const int lr = l & 15, lg = l >> 4;
    const int r0 = wv*16;              // 8 waves x 16 rows = 128 rows

    f32x4 acc1[6] = {};
    #pragma unroll
    for (int s = 0; s < 2; ++s){
        s16x8 af = *(const s16x8*)&As[r0+lr][s*32 + lg*8];
        #pragma unroll
        for (int t = 0; t < 6; ++t){
            s16x8 bf = *(const s16x8*)&Bt1[t*16+lr][s*32 + lg*8];
            acc1[t] = __builtin_amdgcn_mfma_f32_16x16x32_bf16(af, bf, acc1[t], 0, 0, 0);
        }
    }
    #pragma unroll
    for (int t = 0; t < 6; ++t){
        int col = t*16 + lr;
        float bias = sb1[col];
        #pragma unroll
        for (int r = 0; r < 4; ++r)
            sh1[r0 + lg*4 + r][col] = f2b(fmaxf(acc1[t][r] + bias, 0.f));
    }
    __syncthreads();

    f32x4 acc2[3] = {};
    #pragma unroll
    for (int s = 0; s < 3; ++s){
        s16x8 af = *(const s16x8*)&sh1[r0+lr][s*32 + lg*8];
        #pragma unroll
        for (int t = 0; t < 3; ++t){
            s16x8 bf = *(const s16x8*)&Bt2[t*16+lr][s*32 + lg*8];
            acc2[t] = __builtin_amdgcn_mfma_f32_16x16x32_bf16(af, bf, acc2[t], 0, 0, 0);
        }
    }
    size_t gbase = (size_t)blockIdx.x*128;
    // stage outputs (bf16) into sh1 cols 0..47 of this wave's own rows
    #pragma unroll
    for (int r = 0; r < 4; ++r){
        int row = r0 + lg*4 + r;
        float dv = dinv[gbase + row];
        #pragma unroll
        for (int t = 0; t < 3; ++t)
            sh1[row][t*16 + lr] = f2b(acc2[t][r] * dv);
    }
    __syncthreads();
    // repack wave's 16 rows x 16 uints (4 fp8 each), pad cols 48..63 = 0
    #pragma unroll
    for (int it = 0; it < 4; ++it){
        int item = it*64 + l;
        int row = r0 + (item >> 4);
        int c = item & 15;
        uint w = 0;
        if (c < 12){
            float b0 = bl((uint)sh1[row][c*4+0]);
            float b1_ = bl((uint)sh1[row][c*4+1]);
            float b2_ = bl((uint)sh1[row][c*4+2]);
            float b3_ = bl((uint)sh1[row][c*4+3]);
            w = pk4f8(b0, b1_, b2_, b3_);
        }
        ts32[(gbase + row)*16 + c] = w;
    }
}

// ---- conv2 gather: 8 lanes/node x uint2 fp8 (48 real cols), dense-48 masked write ----

__global__ __launch_bounds__(256) void k_gather2(
    const int* __restrict__ rs, const int* __restrict__ re,
    const int* __restrict__ csr, const float* __restrict__ dinv,
    const int* __restrict__ perm,
    const uint2* __restrict__ feat2,   // ts [N] rows of 64B fp8 (48 real)
    const float* __restrict__ bias,
    u16* __restrict__ out)             // agg2 dense [N][48] bf16
{
    int slot = (blockIdx.x*256 + threadIdx.x) >> 3;
    int c4 = threadIdx.x & 7;
    int node = perm[slot];
    uint2 u = feat2[((uint)node << 3) + c4];
    f32x2 s0 = f8lo(u.x), s1 = f8hi(u.x), s2 = f8lo(u.y), s3 = f8hi(u.y);
    float a0 = s0.x, a1 = s0.y, a2 = s1.x, a3 = s1.y;
    float a4 = s2.x, a5 = s2.y, a6 = s3.x, a7 = s3.y;
    int e = rs[node];
    const int e1 = re[node];
    while (e < e1){
        const int last = e1 - 1;
        int idx[8];
        #pragma unroll
        for (int k = 0; k < 8; ++k) idx[k] = csr[min(e + k, last)];
        uint2 uu[8];
        #pragma unroll
        for (int k = 0; k < 8; ++k) uu[k] = feat2[((uint)idx[k] << 3) + c4];
        #pragma unroll
        for (int k = 0; k < 8; ++k){
            if (e + k < e1){
                f32x2 p0 = f8lo(uu[k].x), p1 = f8hi(uu[k].x);
                f32x2 p2 = f8lo(uu[k].y), p3 = f8hi(uu[k].y);
                a0 += p0.x; a1 += p0.y; a2 += p1.x; a3 += p1.y;
                a4 += p2.x; a5 += p2.y; a6 += p3.x; a7 += p3.y;
            }
        }
        e += 8;
    }
    float di = dinv[node];
    if (c4 < 6){
        float4 bz0 = *(const float4*)&bias[8*c4];
        float4 bz1 = *(const float4*)&bias[8*c4 + 4];
        a0 = fmaxf(a0*di + bz0.x, 0.f); a1 = fmaxf(a1*di + bz0.y, 0.f);
        a2 = fmaxf(a2*di + bz0.z, 0.f); a3 = fmaxf(a3*di + bz0.w, 0.f);
        a4 = fmaxf(a4*di + bz1.x, 0.f); a5 = fmaxf(a5*di + bz1.y, 0.f);
        a6 = fmaxf(a6*di + bz1.z, 0.f); a7 = fmaxf(a7*di + bz1.w, 0.f);
        uint4 w;
        w.x = pk(a0,a1); w.y = pk(a2,a3); w.z = pk(a4,a5); w.w = pk(a6,a7);
        *(uint4*)&out[(size_t)node*48 + c4*8] = w;
    }
}

// ---- fused MLP head: 16 graphs/block x 512 blocks (2 blocks/CU), l2 split across waves ----

__global__ __launch_bounds__(512) void k_head(
    const u16* __restrict__ A,      // agg2, graph rows [8192][1920] bf16
    const u16* __restrict__ l1wt,   // [256][1920]
    const float* __restrict__ l1b,
    const u16* __restrict__ l2wt,   // [64][256]
    const float* __restrict__ l2b,
    const float* __restrict__ l3w, const float* __restrict__ l3b,
    float* __restrict__ out)
{
    __shared__ __align__(16) u16 As[16][72];
    __shared__ __align__(16) u16 Bt[256][72];
    __shared__ float part[16][64][2];
    u16 (*sh1)[264] = (u16(*)[264])&Bt[0][0];
    const int tid = threadIdx.x;
    const int g0 = blockIdx.x*16;
    const int w = tid >> 6, l = tid & 63;
    const int lr = l & 15, lg = l >> 4;
    const int c0 = w*32;               // 8 waves x 32 cols = 256
    f32x4 acc[2] = {};
    for (int k0 = 0; k0 < 1920; k0 += 64){
        __syncthreads();
        if (tid < 128){
            int r = tid >> 3, s = tid & 7;
            *(uint4*)&As[r][s*8] = *(const uint4*)&A[(size_t)(g0+r)*1920 + k0 + s*8];
        }
        for (int i = tid; i < 2048; i += 512){
            int n = i >> 3, s = i & 7;
            *(uint4*)&Bt[n][s*8] = *(const uint4*)&l1wt[(size_t)n*1920 + k0 + s*8];
        }
        __syncthreads();
        #pragma unroll
        for (int s = 0; s < 2; ++s){
            s16x8 af = *(const s16x8*)&As[lr][s*32 + lg*8];
            #pragma unroll
            for (int t = 0; t < 2; ++t){
                s16x8 bf = *(const s16x8*)&Bt[c0 + t*16 + lr][s*32 + lg*8];
                acc[t] = __builtin_amdgcn_mfma_f32_16x16x32_bf16(af, bf, acc[t], 0, 0, 0);
            }
        }
    }
    __syncthreads();   // everyone done reading Bt before overlay write
    #pragma unroll
    for (int t = 0; t < 2; ++t){
        int col = c0 + t*16 + lr;
        float bs = l1b[col];
        #pragma unroll
        for (int r = 0; r < 4; ++r)
            sh1[lg*4 + r][col] = f2b(fmaxf(acc[t][r] + bs, 0.f));
    }
    __syncthreads();
    // l2: wave w -> col group (w&3), k-half (w>>2); partials into part[][][kh]
    {
        f32x4 acc2 = {};
        const int col = (w & 3)*16 + lr;
        const int kh = w >> 2;
        #pragma unroll
        for (int s = 0; s < 4; ++s){
            s16x8 af = *(const s16x8*)&sh1[lr][(kh*4 + s)*32 + lg*8];
            s16x8 bf = *(const s16x8*)&l2wt[(size_t)col*256 + (kh*4 + s)*32 + lg*8];
            acc2 = __builtin_amdgcn_mfma_f32_16x16x32_bf16(af, bf, acc2, 0, 0, 0);
        }
        #pragma unroll
        for (int r = 0; r < 4; ++r)
            part[lg*4 + r][col][kh] = acc2[r];
    }
    __syncthreads();
    // final: wave w reduces rows w and w+8 (64 cols each)
    #pragma unroll
    for (int rr = 0; rr < 2; ++rr){
        int row = rr*8 + w;
        float2 pc = *(const float2*)&part[row][l][0];
        float v = fmaxf(pc.x + pc.y + l2b[l], 0.f) * l3w[l];
        #pragma unroll
        for (int o = 32; o; o >>= 1) v += __shfl_xor(v, o);
        if (l == 0)
            out[g0 + row] = 1.0f / (1.0f + expf(-(v + l3b[0])));
    }
}

extern "C" void kernel_launch(void* const* d_in, const int* in_sizes, int n_in,
                              void* d_out, int out_size, void* d_ws, size_t ws_size,
                              hipStream_t stream){
    const float* x   = (const float*)d_in[0];
    const int*   ei  = (const int*)  d_in[1];
    const int*   src = ei;
    const int*   dst = ei + N_EDGES;
    const float* W1  = (const float*)d_in[2];
    const float* b1  = (const float*)d_in[3];
    const float* W2  = (const float*)d_in[4];
    const float* b2  = (const float*)d_in[5];
    const float* l1w = (const float*)d_in[6];
    const float* l1b = (const float*)d_in[7];
    const float* l2w = (const float*)d_in[8];
    const float* l2b = (const float*)d_in[9];
    const float* l3w = (const float*)d_in[10];
    const float* l3b = (const float*)d_in[11];
    float* out = (float*)d_out;

    char* w = (char*)d_ws;
    auto alloc = [&](size_t bytes){ void* p = (void*)w; w += (bytes + 255) & ~(size_t)255; return p; };
    float* dinv    = (float*)alloc((size_t)N_NODES*4);
    int*   rowst   = (int*)  alloc((size_t)N_NODES*4);
    int*   rend    = (int*)  alloc((size_t)N_NODES*4);
    int*   perm    = (int*)  alloc((size_t)N_NODES*4);
    int*   gcur    = (int*)  alloc(NB*4);
    u16*   w1t     = (u16*)  alloc(96*64*2);
    u16*   w2t     = (u16*)  alloc(48*96*2);
    u16*   l1wt    = (u16*)  alloc((size_t)256*1920*2);
    u16*   l2wt    = (u16*)  alloc((size_t)64*256*2);
    int*   csr     = (int*)  alloc((size_t)NB*BCAPE*4);
    uint*  staging = (uint*) alloc((size_t)NB*BCAPE*4);
    char*  BUF_P   = (char*) alloc((size_t)N_NODES*64);     // xs32 -> ts32 (fp8, 21MB)
    char*  BUF_Q   = (char*) alloc((size_t)N_NODES*64*2);   // agg1(fp8) -> agg2(bf16)

    uint* xs32 = (uint*)BUF_P;          // [bucket .. gather1], fp8 [N][64B]
    uint* ts32 = (uint*)BUF_P;          // [conv_mlp .. gather2], fp8 [N][64B]
    uint* agg1 = (uint*)BUF_Q;          // [gather1 .. conv_mlp], fp8 [N][64B]
    u16*  agg2 = (u16*) BUF_Q;          // [gather2 .. head], bf16 dense [N][48]

    // prep: weight transposes + gcur zero (one launch)
    k_prep     <<<129, 256, 0, stream>>>(W1, W2, l1w, l2w, w1t, w2t, l1wt, l2wt, gcur);

    // bucketed CSR build (fixed-cap buckets) + fused fp8 x prescale
    k_partition<<<640, 256, 0, stream>>>(src, dst, gcur, staging);
    k_bucket   <<<640, 512, 0, stream>>>(staging, gcur, x, rowst, rend, dinv, csr, perm, xs32);

    // conv1: fp8 gather -> MFMA conv -> fp8 ts
    k_gather1  <<<10240, 256, 0, stream>>>(rowst, rend, csr, dinv, perm,
                                           (const uint2*)xs32, agg1);
    k_conv_mlp <<<2560,  512, 0, stream>>>(agg1, w1t, b1, w2t, dinv, ts32);

    // conv2: fp8 gather + bias + relu -> dense-48 agg2
    k_gather2  <<<10240, 256, 0, stream>>>(rowst, rend, csr, dinv, perm,
                                           (const uint2*)ts32, b2, agg2);

    // fused MLP head
    k_head     <<<512, 512, 0, stream>>>(agg2, l1wt, l1b, l2wt, l2b, l3w, l3b, out);
}